// Round 17
// baseline (164.489 us; speedup 1.0000x reference)
//
#include <hip/hip_runtime.h>
#include <hip/hip_bf16.h>

using bf16 = __hip_bfloat16;

#define B_  4
#define H_  56
#define W_  56
#define N_  3136
#define C_  256
#define NH  8
#define HD  32
#define P_  49
#define PH  7
#define TOKC 272         // 8 heads * 34 token coefficients
#define KS2  136         // k-window LDS row stride in ushorts (128-ch slice + 8 pad)
#define CPAD 80          // coef LDS row stride (ushorts): 160B, 16B-aligned fragments
#define VTH  60          // vT padded height (y+2 in [0,60))
#define VTW  64          // vT padded width  (x+2 in [0,64))

typedef __attribute__((ext_vector_type(8))) short short8;
typedef __attribute__((ext_vector_type(4))) float f32x4;

union U8 { uint4 u; short8 s; };

__device__ __forceinline__ float bfu2f(ushort u) { return __uint_as_float((uint32_t)u << 16); }
__device__ __forceinline__ ushort f2bf_u(float f) {
    uint32_t u = __float_as_uint(f);
    uint32_t r = (u + 0x7FFFu + ((u >> 16) & 1u)) >> 16;
    return (ushort)r;
}
__device__ __forceinline__ uint32_t pk2(float a, float b) {
    return (uint32_t)f2bf_u(a) | ((uint32_t)f2bf_u(b) << 16);
}
__device__ __forceinline__ float lo16(uint32_t u) { return __uint_as_float(u << 16); }
__device__ __forceinline__ float hi16(uint32_t u) { return __uint_as_float(u & 0xffff0000u); }

__device__ __forceinline__ float half_reduce(float v) {
#pragma unroll
    for (int m = 16; m >= 1; m >>= 1) v += __shfl_xor(v, m);
    return v;
}

__device__ __forceinline__ float block_sum(float val, float* red) {
#pragma unroll
    for (int m = 32; m >= 1; m >>= 1) val += __shfl_xor(val, m);
    __syncthreads();
    if ((threadIdx.x & 63) == 0) red[threadIdx.x >> 6] = val;
    __syncthreads();
    return red[0] + red[1] + red[2] + red[3];
}

// ---------------- prep: weight transposes + tok block-diag + border-zero vT/vpT ----------------
__global__ __launch_bounds__(256) void k_prep(
    const float* __restrict__ Wq, const float* __restrict__ Wkv,
    const float* __restrict__ Wsr, const float* __restrict__ Wproj,
    const float* __restrict__ tok1, const float* __restrict__ bias1,
    const float* __restrict__ tok2, const float* __restrict__ bias2,
    ushort* __restrict__ WT, ushort* __restrict__ WTp,
    ushort* __restrict__ TD, float* __restrict__ biasT,
    ushort* __restrict__ vT, uint32_t* __restrict__ vpT32)
{
    const int gid = blockIdx.x * 256 + threadIdx.x;
    const int gs = gridDim.x * 256;
    for (int i = gid; i < 1024 * 256; i += gs) {
        int o = i >> 8, c = i & 255;
        float w = (o < 256) ? Wq[c * 256 + o]
                : (o < 768) ? Wkv[c * 512 + (o - 256)]
                            : Wsr[c * 256 + (o - 768)];
        WT[i] = f2bf_u(w);
    }
    for (int i = gid; i < 256 * 256; i += gs) {
        int o = i >> 8, c = i & 255;
        WTp[i] = f2bf_u(Wproj[c * 256 + o]);
    }
    for (int i = gid; i < 320 * 256; i += gs) {
        int j = i >> 8, k = i & 255;
        float val = 0.f;
        if (j < TOKC) {
            int h = j / 34, l = j % 34;
            if ((k >> 5) == h) {
                int d = k & 31;
                val = (l < 9) ? tok1[(h * HD + d) * 9 + l]
                              : tok2[(h * HD + d) * 25 + (l - 9)];
            }
        }
        TD[i] = f2bf_u(val);
    }
    for (int i = gid; i < 320; i += gs) {
        float bv = 0.f;
        if (i < TOKC) {
            int h = i / 34, l = i % 34;
            bv = (l < 9) ? bias1[h * 9 + l] : bias2[h * 25 + (l - 9)];
        }
        biasT[i] = bv;
    }
    // zero only the padding border of vT (interior fully overwritten by gemm_in)
    const int nimg = B_ * 256;
    for (int i = gid; i < nimg * 704; i += gs) {
        int img = i / 704, c = i % 704;
        int y, x;
        if (c < 256) { int yi = c >> 6; y = (yi < 2) ? yi : yi + 56; x = c & 63; }
        else { int cc = c - 256; y = 2 + cc / 8; int xx = cc % 8; x = (xx < 2) ? xx : xx + 56; }
        vT[(size_t)img * VTH * VTW + y * VTW + x] = 0;
    }
    for (int i = gid; i < B_ * 256 * 32; i += gs) vpT32[i] = 0u;
}

// ---------------- input GEMM, LDS-free: 64 rows x 256 cols (4 chunks), one mode per blockIdx.y ----
// A fragments loaded direct from xf (f32->bf16 pack) into registers, reused across chunks;
// B fragments read direct from L2-resident WT. No LDS, no barriers.
__global__ __launch_bounds__(256) void k_gemm_in(
    const float* __restrict__ xf,     // [12544][256] f32
    const ushort* __restrict__ WT,    // [1024][256] bf16
    const float* __restrict__ bq, const float* __restrict__ bkv,
    const float* __restrict__ bsr,
    ushort* __restrict__ qnu,
    ushort* __restrict__ knu, ushort* __restrict__ vT, ushort* __restrict__ srgu)
{
    const int r0 = blockIdx.x * 64;
    const int mode = blockIdx.y;
    const int t = threadIdx.x;
    const int w = t >> 6, lane = t & 63;
    const int colq = lane & 15;
    const int k0 = (lane >> 4) * 8;           // element offset within 32-col band
    const int arow = r0 + w * 16 + colq;      // global A row for this thread's fragments
    const int rb = r0 + w * 16 + (lane >> 4) * 4;

    short8 areg[8];
#pragma unroll
    for (int kk = 0; kk < 8; kk++) {
        const float* src = xf + (size_t)arow * 256 + kk * 32 + k0;
        float4 f0 = *(const float4*)(src);
        float4 f1 = *(const float4*)(src + 4);
        U8 u;
        u.u.x = pk2(f0.x, f0.y); u.u.y = pk2(f0.z, f0.w);
        u.u.z = pk2(f1.x, f1.y); u.u.w = pk2(f1.z, f1.w);
        areg[kk] = u.s;
    }

    const float* bp = (mode == 0) ? bq : (mode == 1) ? bkv : (mode == 2) ? (bkv + 256) : bsr;

    for (int cc = 0; cc < 4; cc++) {
        const int cm = cc * 64;
        const int cb = mode * 256 + cm;

        f32x4 acc[4];
#pragma unroll
        for (int ct = 0; ct < 4; ct++) acc[ct] = (f32x4){0.f, 0.f, 0.f, 0.f};
#pragma unroll
        for (int kk = 0; kk < 8; kk++) {
#pragma unroll
            for (int ct = 0; ct < 4; ct++) {
                short8 b = *(const short8*)(WT + (size_t)(cb + ct * 16 + colq) * 256 + kk * 32 + k0);
                acc[ct] = __builtin_amdgcn_mfma_f32_16x16x32_bf16(areg[kk], b, acc[ct], 0, 0, 0);
            }
        }

#pragma unroll
        for (int ct = 0; ct < 4; ct++) {
            float bv = bp[cm + ct * 16 + colq];
#pragma unroll
            for (int j = 0; j < 4; j++) acc[ct][j] += bv;
        }

        if (mode <= 1) {
#pragma unroll
            for (int hp = 0; hp < 2; hp++) {
#pragma unroll
                for (int j = 0; j < 4; j++) {
                    float ss = acc[2 * hp][j] * acc[2 * hp][j] + acc[2 * hp + 1][j] * acc[2 * hp + 1][j];
                    ss += __shfl_xor(ss, 1); ss += __shfl_xor(ss, 2);
                    ss += __shfl_xor(ss, 4); ss += __shfl_xor(ss, 8);
                    float inv = 1.0f / fmaxf(sqrtf(ss), 1e-12f);
                    acc[2 * hp][j] *= inv; acc[2 * hp + 1][j] *= inv;
                }
            }
        } else if (mode == 3) {
#pragma unroll
            for (int ct = 0; ct < 4; ct++)
#pragma unroll
                for (int j = 0; j < 4; j++) {
                    float s = acc[ct][j];
                    acc[ct][j] = 0.5f * s * (1.0f + erff(s * 0.70710678118654752f));
                }
        }

#pragma unroll
        for (int ct = 0; ct < 4; ct++) {
            int gcol = cm + ct * 16 + colq;
#pragma unroll
            for (int j = 0; j < 4; j++) {
                float vvv = acc[ct][j];
                size_t ro = (size_t)(rb + j);
                if (mode == 0)      qnu[ro * 256 + gcol] = f2bf_u(vvv);
                else if (mode == 1) knu[ro * 256 + gcol] = f2bf_u(vvv);
                else if (mode == 2) {
                    int bb = (int)(ro / N_), n = (int)(ro % N_);
                    int yy = n / W_, xx = n % W_;
                    vT[((size_t)(bb * 256 + gcol) * VTH + yy + 2) * VTW + xx + 2] = f2bf_u(vvv);
                } else {
                    srgu[ro * 256 + gcol] = f2bf_u(vvv);
                }
            }
        }
    }
}

// ---------------- proj GEMM, LDS-free: 64 rows x 64 cols per block ----------------
__global__ __launch_bounds__(256) void k_gemm_proj(
    const ushort* __restrict__ Abf,
    const ushort* __restrict__ WT,
    const float*  __restrict__ bias,
    float* __restrict__ dstF)
{
    const int r0 = blockIdx.x * 64;
    const int cb = blockIdx.y * 64;
    const int t = threadIdx.x;
    const int w = t >> 6, lane = t & 63;
    const int colq = lane & 15;
    const int k0 = (lane >> 4) * 8;
    const int arow = r0 + w * 16 + colq;
    const int rb = r0 + w * 16 + (lane >> 4) * 4;

    f32x4 acc[4];
#pragma unroll
    for (int ct = 0; ct < 4; ct++) acc[ct] = (f32x4){0.f, 0.f, 0.f, 0.f};

#pragma unroll
    for (int kk = 0; kk < 8; kk++) {
        short8 a = *(const short8*)(Abf + (size_t)arow * 256 + kk * 32 + k0);
#pragma unroll
        for (int ct = 0; ct < 4; ct++) {
            short8 b = *(const short8*)(WT + (size_t)(cb + ct * 16 + colq) * 256 + kk * 32 + k0);
            acc[ct] = __builtin_amdgcn_mfma_f32_16x16x32_bf16(a, b, acc[ct], 0, 0, 0);
        }
    }

#pragma unroll
    for (int ct = 0; ct < 4; ct++) {
        float bv = bias[cb + ct * 16 + colq];
#pragma unroll
        for (int j = 0; j < 4; j++) acc[ct][j] += bv;
    }

#pragma unroll
    for (int ct = 0; ct < 4; ct++) {
        int gcol = cb + ct * 16 + colq;
#pragma unroll
        for (int j = 0; j < 4; j++)
            dstF[(size_t)(rb + j) * 256 + gcol] = acc[ct][j];
    }
}

// ---------------- srt: pool + LN + kv proj + normalize; vp stored transposed ----------------
__global__ __launch_bounds__(256) void k_srt(
    const uint32_t* __restrict__ srgu32,
    const float* __restrict__ Wkv, const float* __restrict__ bkv,
    const float* __restrict__ ln_g, const float* __restrict__ ln_b,
    ushort* __restrict__ kpn_u, ushort* __restrict__ vpT)
{
    const int cell = blockIdx.x;   // b*P + p
    const int b = cell / P_, p = cell % P_;
    const int py = p / PH, px = p % PH;
    const int t = threadIdx.x;
    const int ph = t >> 7, cp = t & 127;
    __shared__ float xp[C_];
    __shared__ float red[4];

    float sx = 0.f, sy = 0.f;
    for (int k = 0; k < 32; k++) {
        int pi = ph * 32 + k;
        int n = (py * 8 + (pi >> 3)) * W_ + px * 8 + (pi & 7);
        uint32_t u = srgu32[((size_t)b * N_ + n) * 128 + cp];
        sx += lo16(u); sy += hi16(u);
    }
    if (ph == 1) { xp[2 * cp] = sx; xp[2 * cp + 1] = sy; }
    __syncthreads();
    if (ph == 0) {
        xp[2 * cp]     = (xp[2 * cp] + sx) * (1.0f / 64.0f);
        xp[2 * cp + 1] = (xp[2 * cp + 1] + sy) * (1.0f / 64.0f);
    }
    __syncthreads();

    float acc = xp[t];
    float mean = block_sum(acc, red) * (1.0f / C_);
    float dv = acc - mean;
    float var = block_sum(dv * dv, red) * (1.0f / C_);
    float xpv = dv * rsqrtf(var + 1e-5f) * ln_g[t] + ln_b[t];
    __syncthreads();
    xp[t] = xpv;
    __syncthreads();

    float ak = bkv[t];
    float av = bkv[C_ + t];
    for (int c = 0; c < C_; c++) {
        float xv = xp[c];
        ak += xv * Wkv[c * 2 * C_ + t];
        av += xv * Wkv[c * 2 * C_ + C_ + t];
    }
    float nk = fmaxf(sqrtf(half_reduce(ak * ak)), 1e-12f);
    kpn_u[(size_t)cell * C_ + t] = f2bf_u(ak / nk);
    vpT[((size_t)b * 256 + t) * 64 + p] = f2bf_u(av);
}

// ---------------- qkav: MFMA QK + fused tokc MFMA + softmax + MFMA PV ----------------
__global__ __launch_bounds__(256) void k_qkav(
    const ushort* __restrict__ qnu,   // [B*N][256] bf16
    const uint32_t* __restrict__ knu, // [B*N][128] bf16 pairs
    const ushort* __restrict__ kpnu,  // [B*P][256] bf16
    const ushort* __restrict__ TD,    // [320][256] bf16 block-diag tok matrix
    const float* __restrict__ biasT,  // [320] f32
    const ushort* __restrict__ vT,    // [B*256][60][64] bf16, zero-padded image
    const ushort* __restrict__ vpT,   // [B*256][64] bf16, keys padded to 64
    ushort* __restrict__ preu)        // [B*N][256] bf16 out
{
    const int tile = blockIdx.x;          // 0..195
    const int b  = blockIdx.y >> 1;
    const int hs = blockIdx.y & 1;        // heads hs*4 .. hs*4+3
    const int ty = tile / 14, tx = tile % 14;
    const int t = threadIdx.x;

    // ks (64*KS2=8704 us) aliased by coefW [4][16][CPAD] + coefP [4][16][CPAD] (10240 us)
    __shared__ __align__(16) ushort shmem[2 * 4 * 16 * CPAD];
    __shared__ ushort tokcS[16 * 136];
    ushort* ks = shmem;
    ushort* coefW = shmem;
    ushort* coefP = shmem + 4 * 16 * CPAD;

    uint32_t* ks32 = (uint32_t*)ks;
    for (int idx = t; idx < 64 * 32; idx += 256) {
        int r = idx >> 5, u2 = idx & 31;
        int gy = ty * 4 + (r >> 3) - 2, gx = tx * 4 + (r & 7) - 2;
        uint2 kv = make_uint2(0u, 0u);
        if (gy >= 0 && gy < H_ && gx >= 0 && gx < W_)
            kv = *reinterpret_cast<const uint2*>(
                knu + ((size_t)b * N_ + gy * W_ + gx) * 128 + hs * 64 + 2 * u2);
        ks32[r * (KS2 / 2) + 2 * u2]     = kv.x;
        ks32[r * (KS2 / 2) + 2 * u2 + 1] = kv.y;
    }
    __syncthreads();

    const int w = t >> 6, lane = t & 63;
    const int h = hs * 4 + w;
    const int col = lane & 15, kslc = lane >> 4;

    int r8[4], c8[4]; bool inb[4]; int pcl[4]; bool pval[4];
#pragma unroll
    for (int ct = 0; ct < 4; ct++) {
        int key = ct * 16 + col;
        r8[ct] = key >> 3; c8[ct] = key & 7;
        int gy = ty * 4 + r8[ct] - 2, gx = tx * 4 + c8[ct] - 2;
        inb[ct] = (gy >= 0) && (gy < H_) && (gx >= 0) && (gx < W_);
        pval[ct] = key < P_;
        pcl[ct] = pval[ct] ? key : (P_ - 1);
    }

    // QK phase (A: token=col, k-band = head h)
    size_t aflat = (size_t)b * N_ + (ty * 4 + (col >> 2)) * W_ + tx * 4 + (col & 3);
    short8 a = *(const short8*)(qnu + aflat * 256 + h * 32 + kslc * 8);

    f32x4 aw[4], ap[4];
#pragma unroll
    for (int ct = 0; ct < 4; ct++) {
        short8 bw = *(const short8*)(ks + (ct * 16 + col) * KS2 + w * 32 + kslc * 8);
        aw[ct] = __builtin_amdgcn_mfma_f32_16x16x32_bf16(a, bw, (f32x4){0.f,0.f,0.f,0.f}, 0, 0, 0);
        short8 bp = *(const short8*)(kpnu + ((size_t)b * P_ + pcl[ct]) * 256 + h * 32 + kslc * 8);
        ap[ct] = __builtin_amdgcn_mfma_f32_16x16x32_bf16(a, bp, (f32x4){0.f,0.f,0.f,0.f}, 0, 0, 0);
    }

    // fused tokc: same A fragment x TD block-diag (3 ctiles cover 34 cols)
    f32x4 at[3];
#pragma unroll
    for (int ct = 0; ct < 3; ct++) {
        short8 bt = *(const short8*)(TD + (size_t)(h * 34 + ct * 16 + col) * 256 + h * 32 + kslc * 8);
        at[ct] = __builtin_amdgcn_mfma_f32_16x16x32_bf16(a, bt, (f32x4){0.f,0.f,0.f,0.f}, 0, 0, 0);
    }
#pragma unroll
    for (int ct = 0; ct < 3; ct++) {
        int l = ct * 16 + col;
        if (l < 34) {
            float bT = biasT[h * 34 + l];
#pragma unroll
            for (int j = 0; j < 4; j++)
                tokcS[(kslc * 4 + j) * 136 + w * 34 + l] = f2bf_u(at[ct][j] + bT);
        }
    }

    __syncthreads();   // ks reads + tokcS writes done before coef (aliased) writes / tokc reads

    // softmax per token row j (token = (kslc, j)); write coef into A-frag LDS layout
#pragma unroll
    for (int j = 0; j < 4; j++) {
        float mj = -INFINITY;
#pragma unroll
        for (int ct = 0; ct < 4; ct++) {
            int dy = r8[ct] - kslc - 2, dx = c8[ct] - j - 2;
            bool win = inb[ct] && dy >= -2 && dy <= 2 && dx >= -2 && dx <= 2;
            if (win) mj = fmaxf(mj, aw[ct][j]);
            if (pval[ct]) mj = fmaxf(mj, ap[ct][j]);
        }
        mj = fmaxf(mj, __shfl_xor(mj, 1)); mj = fmaxf(mj, __shfl_xor(mj, 2));
        mj = fmaxf(mj, __shfl_xor(mj, 4)); mj = fmaxf(mj, __shfl_xor(mj, 8));
        float ej = 0.f;
        float ew[4], ep[4];
#pragma unroll
        for (int ct = 0; ct < 4; ct++) {
            int dy = r8[ct] - kslc - 2, dx = c8[ct] - j - 2;
            bool win = inb[ct] && dy >= -2 && dy <= 2 && dx >= -2 && dx <= 2;
            bool inner = dy >= -1 && dy <= 1 && dx >= -1 && dx <= 1;
            ew[ct] = win ? (inner ? 2.0f : 1.0f) * __expf(aw[ct][j] - mj) : 0.f;
            ep[ct] = pval[ct] ? __expf(ap[ct][j] - mj) : 0.f;
            ej += ew[ct] + ep[ct];
        }
        ej += __shfl_xor(ej, 1); ej += __shfl_xor(ej, 2);
        ej += __shfl_xor(ej, 4); ej += __shfl_xor(ej, 8);
        float sc = 1.0f / ej;
        const ushort* tokc_j = tokcS + (kslc * 4 + j) * 136 + w * 34;
        const int trow = (w * 16 + kslc * 4 + j) * CPAD;
#pragma unroll
        for (int ct = 0; ct < 4; ct++) {
            int dy = r8[ct] - kslc - 2, dx = c8[ct] - j - 2;
            float cw = 0.f;
            if (dy >= -2 && dy <= 2 && dx >= -2 && dx <= 2) {
                bool inner = dy >= -1 && dy <= 1 && dx >= -1 && dx <= 1;
                int l25 = (dy + 2) * 5 + (dx + 2);
                float tm = bfu2f(tokc_j[9 + l25]);
                if (inner) tm += bfu2f(tokc_j[(dy + 1) * 3 + (dx + 1)]);
                cw = ew[ct] * sc + tm;       // image-OOB: ew=0 -> tm; vT=0 kills it
            }
            coefW[trow + ct * 16 + col] = f2bf_u(cw);
            coefP[trow + ct * 16 + col] = f2bf_u(pval[ct] ? ep[ct] * sc : 0.f);
        }
    }
    __syncthreads();

    // PV phase: per wave = head w; D[tok16][ch32] = coefW·vT + coefP·vpT
    f32x4 accO[2];
    accO[0] = (f32x4){0.f,0.f,0.f,0.f};
    accO[1] = (f32x4){0.f,0.f,0.f,0.f};
    __builtin_amdgcn_s_setprio(1);
#pragma unroll
    for (int kc = 0; kc < 2; kc++) {
        short8 aWf = *(const short8*)(coefW + (w * 16 + col) * CPAD + kc * 32 + kslc * 8);
        short8 aPf = *(const short8*)(coefP + (w * 16 + col) * CPAD + kc * 32 + kslc * 8);
#pragma unroll
        for (int ct = 0; ct < 2; ct++) {
            int chg = hs * 128 + w * 32 + ct * 16 + col;
            size_t vbase = (((size_t)(b * 256 + chg)) * VTH + ty * 4 + kc * 4 + kslc) * VTW + tx * 4;
            uint2 l0 = *(const uint2*)(vT + vbase);
            uint2 l1 = *(const uint2*)(vT + vbase + 4);
            U8 ub; ub.u = make_uint4(l0.x, l0.y, l1.x, l1.y);
            accO[ct] = __builtin_amdgcn_mfma_f32_16x16x32_bf16(aWf, ub.s, accO[ct], 0, 0, 0);
            short8 bPf = *(const short8*)(vpT + ((size_t)b * 256 + chg) * 64 + kc * 32 + kslc * 8);
            accO[ct] = __builtin_amdgcn_mfma_f32_16x16x32_bf16(aPf, bPf, accO[ct], 0, 0, 0);
        }
    }
    __builtin_amdgcn_s_setprio(0);
    // store: C row = kslc*4+j -> token (iy=kslc, ix=j); col -> ch
#pragma unroll
    for (int ct = 0; ct < 2; ct++) {
        int chg = hs * 128 + w * 32 + ct * 16 + col;
#pragma unroll
        for (int j = 0; j < 4; j++) {
            size_t pflat = (size_t)b * N_ + (ty * 4 + kslc) * W_ + tx * 4 + j;
            preu[pflat * 256 + chg] = f2bf_u(accO[ct][j]);
        }
    }
}

extern "C" void kernel_launch(void* const* d_in, const int* in_sizes, int n_in,
                              void* d_out, int out_size, void* d_ws, size_t ws_size,
                              hipStream_t stream)
{
    (void)in_sizes; (void)n_in; (void)out_size; (void)ws_size;
    const float* x     = (const float*)d_in[0];
    const float* Wq    = (const float*)d_in[1];
    const float* bq    = (const float*)d_in[2];
    const float* Wkv   = (const float*)d_in[3];
    const float* bkv   = (const float*)d_in[4];
    const float* Wsr   = (const float*)d_in[5];
    const float* bsr   = (const float*)d_in[6];
    const float* ln_g  = (const float*)d_in[7];
    const float* ln_b  = (const float*)d_in[8];
    const float* tok1  = (const float*)d_in[9];
    const float* bias1 = (const float*)d_in[10];
    const float* tok2  = (const float*)d_in[11];
    const float* bias2 = (const float*)d_in[12];
    const float* Wproj = (const float*)d_in[13];
    const float* bproj = (const float*)d_in[14];
    float* out = (float*)d_out;

    const size_t nhalf = (size_t)B_ * N_ * 128;        // dwords per bf16 plane
    const size_t nvt   = (size_t)B_ * 256 * VTH * VTW; // ushorts

    uint32_t* knu    = (uint32_t*)d_ws;
    uint32_t* srgu   = knu + nhalf;                // sr-gelu plane, reused as pre
    uint32_t* qnu32  = srgu + nhalf;
    ushort*   vTus   = (ushort*)(qnu32 + nhalf);   // zero-padded transposed v image
    ushort*   WTus   = vTus + nvt;                 // 1024*256 bf16
    ushort*   WTpus  = WTus + 1024 * 256;          // 256*256 bf16
    ushort*   TDus   = WTpus + 256 * 256;          // 320*256 bf16
    float*    biasT  = (float*)(TDus + 320 * 256); // 320 f32
    ushort*   vpTus  = (ushort*)(biasT + 320);     // B*256*64 bf16 (transposed vp)
    ushort*   kpnuS  = vpTus + (size_t)B_ * 256 * 64;  // B*P*256 bf16

    ushort* qnu = (ushort*)qnu32;

    k_prep<<<512, 256, 0, stream>>>(Wq, Wkv, Wsr, Wproj, tok1, bias1, tok2, bias2,
                                    WTus, WTpus, TDus, biasT,
                                    vTus, (uint32_t*)vpTus);
    k_gemm_in<<<dim3(196, 4), 256, 0, stream>>>(x, WTus, bq, bkv, bsr,
                                                qnu, (ushort*)knu, vTus, (ushort*)srgu);
    k_srt<<<B_ * P_, 256, 0, stream>>>(srgu, Wkv, bkv, ln_g, ln_b, kpnuS, vpTus);
    k_qkav<<<dim3(196, B_ * 2), 256, 0, stream>>>(qnu, knu, kpnuS, TDus, biasT,
                                                  vTus, vpTus, (ushort*)srgu);
    k_gemm_proj<<<dim3(196, 4), 256, 0, stream>>>((ushort*)srgu, WTpus, bproj, out);
}

// Round 18
// 126.319 us; speedup vs baseline: 1.3022x; 1.3022x over previous
//
#include <hip/hip_runtime.h>
#include <hip/hip_bf16.h>

using bf16 = __hip_bfloat16;

#define B_  4
#define H_  56
#define W_  56
#define N_  3136
#define C_  256
#define NH  8
#define HD  32
#define P_  49
#define PH  7
#define TOKC 272         // 8 heads * 34 token coefficients
#define KS2  136         // k-window LDS row stride in ushorts (128-ch slice + 8 pad)
#define CPAD 80          // coef LDS row stride (ushorts): 160B, 16B-aligned fragments
#define VTH  60          // vT padded height (y+2 in [0,60))
#define VTW  64          // vT padded width  (x+2 in [0,64))

typedef __attribute__((ext_vector_type(8))) short short8;
typedef __attribute__((ext_vector_type(4))) float f32x4;

union U8 { uint4 u; short8 s; };

__device__ __forceinline__ float bfu2f(ushort u) { return __uint_as_float((uint32_t)u << 16); }
__device__ __forceinline__ ushort f2bf_u(float f) {
    uint32_t u = __float_as_uint(f);
    uint32_t r = (u + 0x7FFFu + ((u >> 16) & 1u)) >> 16;
    return (ushort)r;
}
__device__ __forceinline__ uint32_t pk2(float a, float b) {
    return (uint32_t)f2bf_u(a) | ((uint32_t)f2bf_u(b) << 16);
}
__device__ __forceinline__ float lo16(uint32_t u) { return __uint_as_float(u << 16); }
__device__ __forceinline__ float hi16(uint32_t u) { return __uint_as_float(u & 0xffff0000u); }

__device__ __forceinline__ float half_reduce(float v) {
#pragma unroll
    for (int m = 16; m >= 1; m >>= 1) v += __shfl_xor(v, m);
    return v;
}

__device__ __forceinline__ float block_sum(float val, float* red) {
#pragma unroll
    for (int m = 32; m >= 1; m >>= 1) val += __shfl_xor(val, m);
    __syncthreads();
    if ((threadIdx.x & 63) == 0) red[threadIdx.x >> 6] = val;
    __syncthreads();
    return red[0] + red[1] + red[2] + red[3];
}

// ---------------- prep: weight transposes + tok block-diag + border-zero vT/vpT ----------------
__global__ __launch_bounds__(256) void k_prep(
    const float* __restrict__ Wq, const float* __restrict__ Wkv,
    const float* __restrict__ Wsr, const float* __restrict__ Wproj,
    const float* __restrict__ tok1, const float* __restrict__ bias1,
    const float* __restrict__ tok2, const float* __restrict__ bias2,
    ushort* __restrict__ WT, ushort* __restrict__ WTp,
    ushort* __restrict__ TD, float* __restrict__ biasT,
    ushort* __restrict__ vT, uint32_t* __restrict__ vpT32)
{
    const int gid = blockIdx.x * 256 + threadIdx.x;
    const int gs = gridDim.x * 256;
    for (int i = gid; i < 1024 * 256; i += gs) {
        int o = i >> 8, c = i & 255;
        float w = (o < 256) ? Wq[c * 256 + o]
                : (o < 768) ? Wkv[c * 512 + (o - 256)]
                            : Wsr[c * 256 + (o - 768)];
        WT[i] = f2bf_u(w);
    }
    for (int i = gid; i < 256 * 256; i += gs) {
        int o = i >> 8, c = i & 255;
        WTp[i] = f2bf_u(Wproj[c * 256 + o]);
    }
    for (int i = gid; i < 320 * 256; i += gs) {
        int j = i >> 8, k = i & 255;
        float val = 0.f;
        if (j < TOKC) {
            int h = j / 34, l = j % 34;
            if ((k >> 5) == h) {
                int d = k & 31;
                val = (l < 9) ? tok1[(h * HD + d) * 9 + l]
                              : tok2[(h * HD + d) * 25 + (l - 9)];
            }
        }
        TD[i] = f2bf_u(val);
    }
    for (int i = gid; i < 320; i += gs) {
        float bv = 0.f;
        if (i < TOKC) {
            int h = i / 34, l = i % 34;
            bv = (l < 9) ? bias1[h * 9 + l] : bias2[h * 25 + (l - 9)];
        }
        biasT[i] = bv;
    }
    // zero only the padding border of vT (interior fully overwritten by gemm_in)
    const int nimg = B_ * 256;
    for (int i = gid; i < nimg * 704; i += gs) {
        int img = i / 704, c = i % 704;
        int y, x;
        if (c < 256) { int yi = c >> 6; y = (yi < 2) ? yi : yi + 56; x = c & 63; }
        else { int cc = c - 256; y = 2 + cc / 8; int xx = cc % 8; x = (xx < 2) ? xx : xx + 56; }
        vT[(size_t)img * VTH * VTW + y * VTW + x] = 0;
    }
    for (int i = gid; i < B_ * 256 * 32; i += gs) vpT32[i] = 0u;
}

// ---------------- input GEMM: A direct->regs, B staged in LDS; one mode per blockIdx.y ----------
__global__ __launch_bounds__(256) void k_gemm_in(
    const float* __restrict__ xf,     // [12544][256] f32
    const ushort* __restrict__ WT,    // [1024][256] bf16
    const float* __restrict__ bq, const float* __restrict__ bkv,
    const float* __restrict__ bsr,
    ushort* __restrict__ qnu,
    ushort* __restrict__ knu, ushort* __restrict__ vT, ushort* __restrict__ srgu)
{
    const int r0 = blockIdx.x * 64;
    const int mode = blockIdx.y;
    const int t = threadIdx.x;
    __shared__ __align__(16) ushort Bs[64 * 264];

    const int w = t >> 6, lane = t & 63;
    const int colq = lane & 15;
    const int k0 = (lane >> 4) * 8;
    const int arow = r0 + w * 16 + colq;
    const int rb = r0 + w * 16 + (lane >> 4) * 4;

    // A fragments direct from global (f32 -> bf16 pack), one-time
    short8 areg[8];
#pragma unroll
    for (int kk = 0; kk < 8; kk++) {
        const float* src = xf + (size_t)arow * 256 + kk * 32 + k0;
        float4 f0 = *(const float4*)(src);
        float4 f1 = *(const float4*)(src + 4);
        U8 u;
        u.u.x = pk2(f0.x, f0.y); u.u.y = pk2(f0.z, f0.w);
        u.u.z = pk2(f1.x, f1.y); u.u.w = pk2(f1.z, f1.w);
        areg[kk] = u.s;
    }

    const float* bp = (mode == 0) ? bq : (mode == 1) ? bkv : (mode == 2) ? (bkv + 256) : bsr;

    for (int cc = 0; cc < 4; cc++) {
        const int cm = cc * 64;
        const int cb = mode * 256 + cm;

        __syncthreads();   // previous chunk's Bs reads done
#pragma unroll
        for (int i = 0; i < 8; i++) {
            int chunk = t + i * 256;
            int row = chunk >> 5, ks8 = (chunk & 31) * 8;
            *(uint4*)(Bs + row * 264 + ks8) =
                *(const uint4*)(WT + (size_t)(cb + row) * 256 + ks8);
        }
        __syncthreads();

        f32x4 acc[4];
#pragma unroll
        for (int ct = 0; ct < 4; ct++) acc[ct] = (f32x4){0.f, 0.f, 0.f, 0.f};
#pragma unroll
        for (int kk = 0; kk < 8; kk++) {
#pragma unroll
            for (int ct = 0; ct < 4; ct++) {
                short8 b = *(const short8*)(Bs + (ct * 16 + colq) * 264 + kk * 32 + k0);
                acc[ct] = __builtin_amdgcn_mfma_f32_16x16x32_bf16(areg[kk], b, acc[ct], 0, 0, 0);
            }
        }

#pragma unroll
        for (int ct = 0; ct < 4; ct++) {
            float bv = bp[cm + ct * 16 + colq];
#pragma unroll
            for (int j = 0; j < 4; j++) acc[ct][j] += bv;
        }

        if (mode <= 1) {
#pragma unroll
            for (int hp = 0; hp < 2; hp++) {
#pragma unroll
                for (int j = 0; j < 4; j++) {
                    float ss = acc[2 * hp][j] * acc[2 * hp][j] + acc[2 * hp + 1][j] * acc[2 * hp + 1][j];
                    ss += __shfl_xor(ss, 1); ss += __shfl_xor(ss, 2);
                    ss += __shfl_xor(ss, 4); ss += __shfl_xor(ss, 8);
                    float inv = 1.0f / fmaxf(sqrtf(ss), 1e-12f);
                    acc[2 * hp][j] *= inv; acc[2 * hp + 1][j] *= inv;
                }
            }
        } else if (mode == 3) {
#pragma unroll
            for (int ct = 0; ct < 4; ct++)
#pragma unroll
                for (int j = 0; j < 4; j++) {
                    float s = acc[ct][j];
                    acc[ct][j] = 0.5f * s * (1.0f + erff(s * 0.70710678118654752f));
                }
        }

#pragma unroll
        for (int ct = 0; ct < 4; ct++) {
            int gcol = cm + ct * 16 + colq;
#pragma unroll
            for (int j = 0; j < 4; j++) {
                float vvv = acc[ct][j];
                size_t ro = (size_t)(rb + j);
                if (mode == 0)      qnu[ro * 256 + gcol] = f2bf_u(vvv);
                else if (mode == 1) knu[ro * 256 + gcol] = f2bf_u(vvv);
                else if (mode == 2) {
                    int bb = (int)(ro / N_), n = (int)(ro % N_);
                    int yy = n / W_, xx = n % W_;
                    vT[((size_t)(bb * 256 + gcol) * VTH + yy + 2) * VTW + xx + 2] = f2bf_u(vvv);
                } else {
                    srgu[ro * 256 + gcol] = f2bf_u(vvv);
                }
            }
        }
    }
}

// ---------------- proj GEMM: A direct->regs, B staged in LDS ----------------
__global__ __launch_bounds__(256) void k_gemm_proj(
    const ushort* __restrict__ Abf,
    const ushort* __restrict__ WT,
    const float*  __restrict__ bias,
    float* __restrict__ dstF)
{
    const int r0 = blockIdx.x * 64;
    const int cb = blockIdx.y * 64;
    const int t = threadIdx.x;
    __shared__ __align__(16) ushort Bs[64 * 264];

    const int w = t >> 6, lane = t & 63;
    const int colq = lane & 15;
    const int k0 = (lane >> 4) * 8;
    const int arow = r0 + w * 16 + colq;
    const int rb = r0 + w * 16 + (lane >> 4) * 4;

#pragma unroll
    for (int i = 0; i < 8; i++) {
        int chunk = t + i * 256;
        int row = chunk >> 5, ks = (chunk & 31) * 8;
        *(uint4*)(Bs + row * 264 + ks) = *(const uint4*)(WT + (size_t)(cb + row) * 256 + ks);
    }

    short8 areg[8];
#pragma unroll
    for (int kk = 0; kk < 8; kk++)
        areg[kk] = *(const short8*)(Abf + (size_t)arow * 256 + kk * 32 + k0);

    __syncthreads();

    f32x4 acc[4];
#pragma unroll
    for (int ct = 0; ct < 4; ct++) acc[ct] = (f32x4){0.f, 0.f, 0.f, 0.f};

#pragma unroll
    for (int kk = 0; kk < 8; kk++) {
#pragma unroll
        for (int ct = 0; ct < 4; ct++) {
            short8 b = *(const short8*)(Bs + (ct * 16 + colq) * 264 + kk * 32 + k0);
            acc[ct] = __builtin_amdgcn_mfma_f32_16x16x32_bf16(areg[kk], b, acc[ct], 0, 0, 0);
        }
    }

#pragma unroll
    for (int ct = 0; ct < 4; ct++) {
        float bv = bias[cb + ct * 16 + colq];
#pragma unroll
        for (int j = 0; j < 4; j++) acc[ct][j] += bv;
    }

#pragma unroll
    for (int ct = 0; ct < 4; ct++) {
        int gcol = cb + ct * 16 + colq;
#pragma unroll
        for (int j = 0; j < 4; j++)
            dstF[(size_t)(rb + j) * 256 + gcol] = acc[ct][j];
    }
}

// ---------------- srt: pool + LN + kv proj + normalize; vp stored transposed ----------------
__global__ __launch_bounds__(256) void k_srt(
    const uint32_t* __restrict__ srgu32,
    const float* __restrict__ Wkv, const float* __restrict__ bkv,
    const float* __restrict__ ln_g, const float* __restrict__ ln_b,
    ushort* __restrict__ kpn_u, ushort* __restrict__ vpT)
{
    const int cell = blockIdx.x;   // b*P + p
    const int b = cell / P_, p = cell % P_;
    const int py = p / PH, px = p % PH;
    const int t = threadIdx.x;
    const int ph = t >> 7, cp = t & 127;
    __shared__ float xp[C_];
    __shared__ float red[4];

    float sx = 0.f, sy = 0.f;
    for (int k = 0; k < 32; k++) {
        int pi = ph * 32 + k;
        int n = (py * 8 + (pi >> 3)) * W_ + px * 8 + (pi & 7);
        uint32_t u = srgu32[((size_t)b * N_ + n) * 128 + cp];
        sx += lo16(u); sy += hi16(u);
    }
    if (ph == 1) { xp[2 * cp] = sx; xp[2 * cp + 1] = sy; }
    __syncthreads();
    if (ph == 0) {
        xp[2 * cp]     = (xp[2 * cp] + sx) * (1.0f / 64.0f);
        xp[2 * cp + 1] = (xp[2 * cp + 1] + sy) * (1.0f / 64.0f);
    }
    __syncthreads();

    float acc = xp[t];
    float mean = block_sum(acc, red) * (1.0f / C_);
    float dv = acc - mean;
    float var = block_sum(dv * dv, red) * (1.0f / C_);
    float xpv = dv * rsqrtf(var + 1e-5f) * ln_g[t] + ln_b[t];
    __syncthreads();
    xp[t] = xpv;
    __syncthreads();

    float ak = bkv[t];
    float av = bkv[C_ + t];
    for (int c = 0; c < C_; c++) {
        float xv = xp[c];
        ak += xv * Wkv[c * 2 * C_ + t];
        av += xv * Wkv[c * 2 * C_ + C_ + t];
    }
    float nk = fmaxf(sqrtf(half_reduce(ak * ak)), 1e-12f);
    kpn_u[(size_t)cell * C_ + t] = f2bf_u(ak / nk);
    vpT[((size_t)b * 256 + t) * 64 + p] = f2bf_u(av);
}

// ---------------- qkav: MFMA QK + fused tokc MFMA + softmax + MFMA PV ----------------
__global__ __launch_bounds__(256) void k_qkav(
    const ushort* __restrict__ qnu,   // [B*N][256] bf16
    const uint32_t* __restrict__ knu, // [B*N][128] bf16 pairs
    const ushort* __restrict__ kpnu,  // [B*P][256] bf16
    const ushort* __restrict__ TD,    // [320][256] bf16 block-diag tok matrix
    const float* __restrict__ biasT,  // [320] f32
    const ushort* __restrict__ vT,    // [B*256][60][64] bf16, zero-padded image
    const ushort* __restrict__ vpT,   // [B*256][64] bf16, keys padded to 64
    ushort* __restrict__ preu)        // [B*N][256] bf16 out
{
    const int tile = blockIdx.x;          // 0..195
    const int b  = blockIdx.y >> 1;
    const int hs = blockIdx.y & 1;        // heads hs*4 .. hs*4+3
    const int ty = tile / 14, tx = tile % 14;
    const int t = threadIdx.x;

    // ks (64*KS2=8704 us) aliased by coefW [4][16][CPAD] + coefP [4][16][CPAD] (10240 us)
    __shared__ __align__(16) ushort shmem[2 * 4 * 16 * CPAD];
    __shared__ ushort tokcS[16 * 136];
    ushort* ks = shmem;
    ushort* coefW = shmem;
    ushort* coefP = shmem + 4 * 16 * CPAD;

    uint32_t* ks32 = (uint32_t*)ks;
    for (int idx = t; idx < 64 * 32; idx += 256) {
        int r = idx >> 5, u2 = idx & 31;
        int gy = ty * 4 + (r >> 3) - 2, gx = tx * 4 + (r & 7) - 2;
        uint2 kv = make_uint2(0u, 0u);
        if (gy >= 0 && gy < H_ && gx >= 0 && gx < W_)
            kv = *reinterpret_cast<const uint2*>(
                knu + ((size_t)b * N_ + gy * W_ + gx) * 128 + hs * 64 + 2 * u2);
        ks32[r * (KS2 / 2) + 2 * u2]     = kv.x;
        ks32[r * (KS2 / 2) + 2 * u2 + 1] = kv.y;
    }
    __syncthreads();

    const int w = t >> 6, lane = t & 63;
    const int h = hs * 4 + w;
    const int col = lane & 15, kslc = lane >> 4;

    int r8[4], c8[4]; bool inb[4]; int pcl[4]; bool pval[4];
#pragma unroll
    for (int ct = 0; ct < 4; ct++) {
        int key = ct * 16 + col;
        r8[ct] = key >> 3; c8[ct] = key & 7;
        int gy = ty * 4 + r8[ct] - 2, gx = tx * 4 + c8[ct] - 2;
        inb[ct] = (gy >= 0) && (gy < H_) && (gx >= 0) && (gx < W_);
        pval[ct] = key < P_;
        pcl[ct] = pval[ct] ? key : (P_ - 1);
    }

    // QK phase (A: token=col, k-band = head h)
    size_t aflat = (size_t)b * N_ + (ty * 4 + (col >> 2)) * W_ + tx * 4 + (col & 3);
    short8 a = *(const short8*)(qnu + aflat * 256 + h * 32 + kslc * 8);

    f32x4 aw[4], ap[4];
#pragma unroll
    for (int ct = 0; ct < 4; ct++) {
        short8 bw = *(const short8*)(ks + (ct * 16 + col) * KS2 + w * 32 + kslc * 8);
        aw[ct] = __builtin_amdgcn_mfma_f32_16x16x32_bf16(a, bw, (f32x4){0.f,0.f,0.f,0.f}, 0, 0, 0);
        short8 bp = *(const short8*)(kpnu + ((size_t)b * P_ + pcl[ct]) * 256 + h * 32 + kslc * 8);
        ap[ct] = __builtin_amdgcn_mfma_f32_16x16x32_bf16(a, bp, (f32x4){0.f,0.f,0.f,0.f}, 0, 0, 0);
    }

    // fused tokc: same A fragment x TD block-diag (3 ctiles cover 34 cols)
    f32x4 at[3];
#pragma unroll
    for (int ct = 0; ct < 3; ct++) {
        short8 bt = *(const short8*)(TD + (size_t)(h * 34 + ct * 16 + col) * 256 + h * 32 + kslc * 8);
        at[ct] = __builtin_amdgcn_mfma_f32_16x16x32_bf16(a, bt, (f32x4){0.f,0.f,0.f,0.f}, 0, 0, 0);
    }
#pragma unroll
    for (int ct = 0; ct < 3; ct++) {
        int l = ct * 16 + col;
        if (l < 34) {
            float bT = biasT[h * 34 + l];
#pragma unroll
            for (int j = 0; j < 4; j++)
                tokcS[(kslc * 4 + j) * 136 + w * 34 + l] = f2bf_u(at[ct][j] + bT);
        }
    }

    __syncthreads();   // ks reads + tokcS writes done before coef (aliased) writes / tokc reads

    // softmax per token row j (token = (kslc, j)); write coef into A-frag LDS layout
#pragma unroll
    for (int j = 0; j < 4; j++) {
        float mj = -INFINITY;
#pragma unroll
        for (int ct = 0; ct < 4; ct++) {
            int dy = r8[ct] - kslc - 2, dx = c8[ct] - j - 2;
            bool win = inb[ct] && dy >= -2 && dy <= 2 && dx >= -2 && dx <= 2;
            if (win) mj = fmaxf(mj, aw[ct][j]);
            if (pval[ct]) mj = fmaxf(mj, ap[ct][j]);
        }
        mj = fmaxf(mj, __shfl_xor(mj, 1)); mj = fmaxf(mj, __shfl_xor(mj, 2));
        mj = fmaxf(mj, __shfl_xor(mj, 4)); mj = fmaxf(mj, __shfl_xor(mj, 8));
        float ej = 0.f;
        float ew[4], ep[4];
#pragma unroll
        for (int ct = 0; ct < 4; ct++) {
            int dy = r8[ct] - kslc - 2, dx = c8[ct] - j - 2;
            bool win = inb[ct] && dy >= -2 && dy <= 2 && dx >= -2 && dx <= 2;
            bool inner = dy >= -1 && dy <= 1 && dx >= -1 && dx <= 1;
            ew[ct] = win ? (inner ? 2.0f : 1.0f) * __expf(aw[ct][j] - mj) : 0.f;
            ep[ct] = pval[ct] ? __expf(ap[ct][j] - mj) : 0.f;
            ej += ew[ct] + ep[ct];
        }
        ej += __shfl_xor(ej, 1); ej += __shfl_xor(ej, 2);
        ej += __shfl_xor(ej, 4); ej += __shfl_xor(ej, 8);
        float sc = 1.0f / ej;
        const ushort* tokc_j = tokcS + (kslc * 4 + j) * 136 + w * 34;
        const int trow = (w * 16 + kslc * 4 + j) * CPAD;
#pragma unroll
        for (int ct = 0; ct < 4; ct++) {
            int dy = r8[ct] - kslc - 2, dx = c8[ct] - j - 2;
            float cw = 0.f;
            if (dy >= -2 && dy <= 2 && dx >= -2 && dx <= 2) {
                bool inner = dy >= -1 && dy <= 1 && dx >= -1 && dx <= 1;
                int l25 = (dy + 2) * 5 + (dx + 2);
                float tm = bfu2f(tokc_j[9 + l25]);
                if (inner) tm += bfu2f(tokc_j[(dy + 1) * 3 + (dx + 1)]);
                cw = ew[ct] * sc + tm;       // image-OOB: ew=0 -> tm; vT=0 kills it
            }
            coefW[trow + ct * 16 + col] = f2bf_u(cw);
            coefP[trow + ct * 16 + col] = f2bf_u(pval[ct] ? ep[ct] * sc : 0.f);
        }
    }
    __syncthreads();

    // PV phase: per wave = head w; D[tok16][ch32] = coefW·vT + coefP·vpT
    f32x4 accO[2];
    accO[0] = (f32x4){0.f,0.f,0.f,0.f};
    accO[1] = (f32x4){0.f,0.f,0.f,0.f};
    __builtin_amdgcn_s_setprio(1);
#pragma unroll
    for (int kc = 0; kc < 2; kc++) {
        short8 aWf = *(const short8*)(coefW + (w * 16 + col) * CPAD + kc * 32 + kslc * 8);
        short8 aPf = *(const short8*)(coefP + (w * 16 + col) * CPAD + kc * 32 + kslc * 8);
#pragma unroll
        for (int ct = 0; ct < 2; ct++) {
            int chg = hs * 128 + w * 32 + ct * 16 + col;
            size_t vbase = (((size_t)(b * 256 + chg)) * VTH + ty * 4 + kc * 4 + kslc) * VTW + tx * 4;
            uint2 l0 = *(const uint2*)(vT + vbase);
            uint2 l1 = *(const uint2*)(vT + vbase + 4);
            U8 ub; ub.u = make_uint4(l0.x, l0.y, l1.x, l1.y);
            accO[ct] = __builtin_amdgcn_mfma_f32_16x16x32_bf16(aWf, ub.s, accO[ct], 0, 0, 0);
            short8 bPf = *(const short8*)(vpT + ((size_t)b * 256 + chg) * 64 + kc * 32 + kslc * 8);
            accO[ct] = __builtin_amdgcn_mfma_f32_16x16x32_bf16(aPf, bPf, accO[ct], 0, 0, 0);
        }
    }
    __builtin_amdgcn_s_setprio(0);
    // store: C row = kslc*4+j -> token (iy=kslc, ix=j); col -> ch
#pragma unroll
    for (int ct = 0; ct < 2; ct++) {
        int chg = hs * 128 + w * 32 + ct * 16 + col;
#pragma unroll
        for (int j = 0; j < 4; j++) {
            size_t pflat = (size_t)b * N_ + (ty * 4 + kslc) * W_ + tx * 4 + j;
            preu[pflat * 256 + chg] = f2bf_u(accO[ct][j]);
        }
    }
}

extern "C" void kernel_launch(void* const* d_in, const int* in_sizes, int n_in,
                              void* d_out, int out_size, void* d_ws, size_t ws_size,
                              hipStream_t stream)
{
    (void)in_sizes; (void)n_in; (void)out_size; (void)ws_size;
    const float* x     = (const float*)d_in[0];
    const float* Wq    = (const float*)d_in[1];
    const float* bq    = (const float*)d_in[2];
    const float* Wkv   = (const float*)d_in[3];
    const float* bkv   = (const float*)d_in[4];
    const float* Wsr   = (const float*)d_in[5];
    const float* bsr   = (const float*)d_in[6];
    const float* ln_g  = (const float*)d_in[7];
    const float* ln_b  = (const float*)d_in[8];
    const float* tok1  = (const float*)d_in[9];
    const float* bias1 = (const float*)d_in[10];
    const float* tok2  = (const float*)d_in[11];
    const float* bias2 = (const float*)d_in[12];
    const float* Wproj = (const float*)d_in[13];
    const float* bproj = (const float*)d_in[14];
    float* out = (float*)d_out;

    const size_t nhalf = (size_t)B_ * N_ * 128;        // dwords per bf16 plane
    const size_t nvt   = (size_t)B_ * 256 * VTH * VTW; // ushorts

    uint32_t* knu    = (uint32_t*)d_ws;
    uint32_t* srgu   = knu + nhalf;                // sr-gelu plane, reused as pre
    uint32_t* qnu32  = srgu + nhalf;
    ushort*   vTus   = (ushort*)(qnu32 + nhalf);   // zero-padded transposed v image
    ushort*   WTus   = vTus + nvt;                 // 1024*256 bf16
    ushort*   WTpus  = WTus + 1024 * 256;          // 256*256 bf16
    ushort*   TDus   = WTpus + 256 * 256;          // 320*256 bf16
    float*    biasT  = (float*)(TDus + 320 * 256); // 320 f32
    ushort*   vpTus  = (ushort*)(biasT + 320);     // B*256*64 bf16 (transposed vp)
    ushort*   kpnuS  = vpTus + (size_t)B_ * 256 * 64;  // B*P*256 bf16

    ushort* qnu = (ushort*)qnu32;

    k_prep<<<512, 256, 0, stream>>>(Wq, Wkv, Wsr, Wproj, tok1, bias1, tok2, bias2,
                                    WTus, WTpus, TDus, biasT,
                                    vTus, (uint32_t*)vpTus);
    k_gemm_in<<<dim3(196, 4), 256, 0, stream>>>(x, WTus, bq, bkv, bsr,
                                                qnu, (ushort*)knu, vTus, (ushort*)srgu);
    k_srt<<<B_ * P_, 256, 0, stream>>>(srgu, Wkv, bkv, ln_g, ln_b, kpnuS, vpTus);
    k_qkav<<<dim3(196, B_ * 2), 256, 0, stream>>>(qnu, knu, kpnuS, TDus, biasT,
                                                  vTus, vpTus, (ushort*)srgu);
    k_gemm_proj<<<dim3(196, 4), 256, 0, stream>>>((ushort*)srgu, WTpus, bproj, out);
}

// Round 19
// 109.663 us; speedup vs baseline: 1.4999x; 1.1519x over previous
//
#include <hip/hip_runtime.h>
#include <hip/hip_bf16.h>

using bf16 = __hip_bfloat16;

#define B_  4
#define H_  56
#define W_  56
#define N_  3136
#define C_  256
#define NH  8
#define HD  32
#define P_  49
#define PH  7
#define TOKC 272         // 8 heads * 34 token coefficients
#define KS2  136         // k-window LDS row stride in ushorts (128-ch slice + 8 pad)
#define CPAD 80          // coef LDS row stride (ushorts): 160B, 16B-aligned fragments
#define VTH  60          // vT padded height (y+2 in [0,60))
#define VTW  64          // vT padded width  (x+2 in [0,64))

typedef __attribute__((ext_vector_type(8))) short short8;
typedef __attribute__((ext_vector_type(4))) float f32x4;

union U8 { uint4 u; short8 s; };

__device__ __forceinline__ float bfu2f(ushort u) { return __uint_as_float((uint32_t)u << 16); }
__device__ __forceinline__ ushort f2bf_u(float f) {
    uint32_t u = __float_as_uint(f);
    uint32_t r = (u + 0x7FFFu + ((u >> 16) & 1u)) >> 16;
    return (ushort)r;
}
__device__ __forceinline__ uint32_t pk2(float a, float b) {
    return (uint32_t)f2bf_u(a) | ((uint32_t)f2bf_u(b) << 16);
}
__device__ __forceinline__ float lo16(uint32_t u) { return __uint_as_float(u << 16); }
__device__ __forceinline__ float hi16(uint32_t u) { return __uint_as_float(u & 0xffff0000u); }

__device__ __forceinline__ float half_reduce(float v) {
#pragma unroll
    for (int m = 16; m >= 1; m >>= 1) v += __shfl_xor(v, m);
    return v;
}

__device__ __forceinline__ float block_sum(float val, float* red) {
#pragma unroll
    for (int m = 32; m >= 1; m >>= 1) val += __shfl_xor(val, m);
    __syncthreads();
    if ((threadIdx.x & 63) == 0) red[threadIdx.x >> 6] = val;
    __syncthreads();
    return red[0] + red[1] + red[2] + red[3];
}

// ---------------- prep: weight transposes + tok block-diag + border-zero vT/vpT ----------------
__global__ __launch_bounds__(256) void k_prep(
    const float* __restrict__ Wq, const float* __restrict__ Wkv,
    const float* __restrict__ Wsr, const float* __restrict__ Wproj,
    const float* __restrict__ tok1, const float* __restrict__ bias1,
    const float* __restrict__ tok2, const float* __restrict__ bias2,
    ushort* __restrict__ WT, ushort* __restrict__ WTp,
    ushort* __restrict__ TD, float* __restrict__ biasT,
    ushort* __restrict__ vT, uint32_t* __restrict__ vpT32)
{
    const int gid = blockIdx.x * 256 + threadIdx.x;
    const int gs = gridDim.x * 256;
    for (int i = gid; i < 1024 * 256; i += gs) {
        int o = i >> 8, c = i & 255;
        float w = (o < 256) ? Wq[c * 256 + o]
                : (o < 768) ? Wkv[c * 512 + (o - 256)]
                            : Wsr[c * 256 + (o - 768)];
        WT[i] = f2bf_u(w);
    }
    for (int i = gid; i < 256 * 256; i += gs) {
        int o = i >> 8, c = i & 255;
        WTp[i] = f2bf_u(Wproj[c * 256 + o]);
    }
    for (int i = gid; i < 320 * 256; i += gs) {
        int j = i >> 8, k = i & 255;
        float val = 0.f;
        if (j < TOKC) {
            int h = j / 34, l = j % 34;
            if ((k >> 5) == h) {
                int d = k & 31;
                val = (l < 9) ? tok1[(h * HD + d) * 9 + l]
                              : tok2[(h * HD + d) * 25 + (l - 9)];
            }
        }
        TD[i] = f2bf_u(val);
    }
    for (int i = gid; i < 320; i += gs) {
        float bv = 0.f;
        if (i < TOKC) {
            int h = i / 34, l = i % 34;
            bv = (l < 9) ? bias1[h * 9 + l] : bias2[h * 25 + (l - 9)];
        }
        biasT[i] = bv;
    }
    // zero only the padding border of vT (interior fully overwritten by gemm_in)
    const int nimg = B_ * 256;
    for (int i = gid; i < nimg * 704; i += gs) {
        int img = i / 704, c = i % 704;
        int y, x;
        if (c < 256) { int yi = c >> 6; y = (yi < 2) ? yi : yi + 56; x = c & 63; }
        else { int cc = c - 256; y = 2 + cc / 8; int xx = cc % 8; x = (xx < 2) ? xx : xx + 56; }
        vT[(size_t)img * VTH * VTW + y * VTW + x] = 0;
    }
    for (int i = gid; i < B_ * 256 * 32; i += gs) vpT32[i] = 0u;
}

// ---------------- merged input GEMM: 64 rows x 512 cols (8 chunks), K=256 ----------------
// (round-13 proven structure: A+B LDS-staged, direct Bs staging, scattered vT store)
__global__ __launch_bounds__(256) void k_gemm_in(
    const float* __restrict__ xf,     // [12544][256] f32
    const ushort* __restrict__ WT,    // [1024][256] bf16
    const float* __restrict__ bq, const float* __restrict__ bkv,
    const float* __restrict__ bsr,
    ushort* __restrict__ qnu,
    ushort* __restrict__ knu, ushort* __restrict__ vT, ushort* __restrict__ srgu)
{
    const int r0 = blockIdx.x * 64;
    const int halfy = blockIdx.y;
    const int t = threadIdx.x;
    __shared__ __align__(16) ushort As[64 * 264];
    __shared__ __align__(16) ushort Bs[64 * 264];

#pragma unroll
    for (int i = 0; i < 8; i++) {
        int chunk = t + i * 256;
        int row = chunk >> 5, ks8 = (chunk & 31) * 8;
        const float* src = xf + (size_t)(r0 + row) * 256 + ks8;
        float4 f0 = *(const float4*)(src);
        float4 f1 = *(const float4*)(src + 4);
        uint4 o;
        o.x = pk2(f0.x, f0.y); o.y = pk2(f0.z, f0.w);
        o.z = pk2(f1.x, f1.y); o.w = pk2(f1.z, f1.w);
        *(uint4*)(As + row * 264 + ks8) = o;
    }
    __syncthreads();

    const int w = t >> 6, lane = t & 63;
    const int arow = w * 16 + (lane & 15);
    const int k0 = (lane >> 4) * 8;
    const int colq = lane & 15;
    const int rb = r0 + w * 16 + (lane >> 4) * 4;

    short8 areg[8];
#pragma unroll
    for (int kk = 0; kk < 8; kk++)
        areg[kk] = *(const short8*)(As + arow * 264 + kk * 32 + k0);

    for (int cc = 0; cc < 8; cc++) {
        const int cb = halfy * 512 + cc * 64;
        const int mode = cb >> 8;
        const int cm = cb & 255;

        __syncthreads();   // previous chunk's Bs reads done
#pragma unroll
        for (int i = 0; i < 8; i++) {
            int chunk = t + i * 256;
            int row = chunk >> 5, ks8 = (chunk & 31) * 8;
            *(uint4*)(Bs + row * 264 + ks8) =
                *(const uint4*)(WT + (size_t)(cb + row) * 256 + ks8);
        }
        __syncthreads();

        f32x4 acc[4];
#pragma unroll
        for (int ct = 0; ct < 4; ct++) acc[ct] = (f32x4){0.f, 0.f, 0.f, 0.f};
#pragma unroll
        for (int kk = 0; kk < 8; kk++) {
#pragma unroll
            for (int ct = 0; ct < 4; ct++) {
                short8 b = *(const short8*)(Bs + (ct * 16 + colq) * 264 + kk * 32 + k0);
                acc[ct] = __builtin_amdgcn_mfma_f32_16x16x32_bf16(areg[kk], b, acc[ct], 0, 0, 0);
            }
        }

        const float* bp = (mode == 0) ? bq : (mode == 1) ? bkv : (mode == 2) ? (bkv + 256) : bsr;
#pragma unroll
        for (int ct = 0; ct < 4; ct++) {
            float bv = bp[cm + ct * 16 + colq];
#pragma unroll
            for (int j = 0; j < 4; j++) acc[ct][j] += bv;
        }

        if (mode <= 1) {
#pragma unroll
            for (int hp = 0; hp < 2; hp++) {
#pragma unroll
                for (int j = 0; j < 4; j++) {
                    float ss = acc[2 * hp][j] * acc[2 * hp][j] + acc[2 * hp + 1][j] * acc[2 * hp + 1][j];
                    ss += __shfl_xor(ss, 1); ss += __shfl_xor(ss, 2);
                    ss += __shfl_xor(ss, 4); ss += __shfl_xor(ss, 8);
                    float inv = 1.0f / fmaxf(sqrtf(ss), 1e-12f);
                    acc[2 * hp][j] *= inv; acc[2 * hp + 1][j] *= inv;
                }
            }
        } else if (mode == 3) {
#pragma unroll
            for (int ct = 0; ct < 4; ct++)
#pragma unroll
                for (int j = 0; j < 4; j++) {
                    float s = acc[ct][j];
                    acc[ct][j] = 0.5f * s * (1.0f + erff(s * 0.70710678118654752f));
                }
        }

#pragma unroll
        for (int ct = 0; ct < 4; ct++) {
            int gcol = cm + ct * 16 + colq;
#pragma unroll
            for (int j = 0; j < 4; j++) {
                float vvv = acc[ct][j];
                size_t ro = (size_t)(rb + j);
                if (mode == 0)      qnu[ro * 256 + gcol] = f2bf_u(vvv);
                else if (mode == 1) knu[ro * 256 + gcol] = f2bf_u(vvv);
                else if (mode == 2) {
                    int bb = (int)(ro / N_), n = (int)(ro % N_);
                    int yy = n / W_, xx = n % W_;
                    vT[((size_t)(bb * 256 + gcol) * VTH + yy + 2) * VTW + xx + 2] = f2bf_u(vvv);
                } else {
                    srgu[ro * 256 + gcol] = f2bf_u(vvv);
                }
            }
        }
    }
}

// ---------------- bf16-A GEMM 64x64 tile, K=256 (proj, f32 -> out) ----------------
__global__ __launch_bounds__(256) void k_gemm_proj(
    const ushort* __restrict__ Abf,
    const ushort* __restrict__ WT,
    const float*  __restrict__ bias,
    float* __restrict__ dstF)
{
    const int r0 = blockIdx.x * 64;
    const int cb = blockIdx.y * 64;
    const int t = threadIdx.x;
    __shared__ __align__(16) ushort As[64 * 264];
    __shared__ __align__(16) ushort Bs[64 * 264];

#pragma unroll
    for (int i = 0; i < 8; i++) {
        int chunk = t + i * 256;
        int row = chunk >> 5, ks = (chunk & 31) * 8;
        *(uint4*)(As + row * 264 + ks) = *(const uint4*)(Abf + (size_t)(r0 + row) * 256 + ks);
        *(uint4*)(Bs + row * 264 + ks) = *(const uint4*)(WT + (size_t)(cb + row) * 256 + ks);
    }
    __syncthreads();

    const int w = t >> 6, lane = t & 63;
    const int arow = w * 16 + (lane & 15);
    const int k0 = (lane >> 4) * 8;
    f32x4 acc[4];
#pragma unroll
    for (int ct = 0; ct < 4; ct++) acc[ct] = (f32x4){0.f, 0.f, 0.f, 0.f};

#pragma unroll
    for (int kk = 0; kk < 8; kk++) {
        short8 a = *(const short8*)(As + arow * 264 + kk * 32 + k0);
#pragma unroll
        for (int ct = 0; ct < 4; ct++) {
            short8 b = *(const short8*)(Bs + (ct * 16 + (lane & 15)) * 264 + kk * 32 + k0);
            acc[ct] = __builtin_amdgcn_mfma_f32_16x16x32_bf16(a, b, acc[ct], 0, 0, 0);
        }
    }

    const int colq = lane & 15;
    const int rb = r0 + w * 16 + (lane >> 4) * 4;
#pragma unroll
    for (int ct = 0; ct < 4; ct++) {
        float bv = bias[cb + ct * 16 + colq];
#pragma unroll
        for (int j = 0; j < 4; j++) acc[ct][j] += bv;
    }

#pragma unroll
    for (int ct = 0; ct < 4; ct++) {
        int gcol = cb + ct * 16 + colq;
#pragma unroll
        for (int j = 0; j < 4; j++)
            dstF[(size_t)(rb + j) * 256 + gcol] = acc[ct][j];
    }
}

// ---------------- srt: pool + LN + kv proj + normalize; vp stored transposed ----------------
__global__ __launch_bounds__(256) void k_srt(
    const uint32_t* __restrict__ srgu32,
    const float* __restrict__ Wkv, const float* __restrict__ bkv,
    const float* __restrict__ ln_g, const float* __restrict__ ln_b,
    ushort* __restrict__ kpn_u, ushort* __restrict__ vpT)
{
    const int cell = blockIdx.x;   // b*P + p
    const int b = cell / P_, p = cell % P_;
    const int py = p / PH, px = p % PH;
    const int t = threadIdx.x;
    const int ph = t >> 7, cp = t & 127;
    __shared__ float xp[C_];
    __shared__ float red[4];

    float sx = 0.f, sy = 0.f;
    for (int k = 0; k < 32; k++) {
        int pi = ph * 32 + k;
        int n = (py * 8 + (pi >> 3)) * W_ + px * 8 + (pi & 7);
        uint32_t u = srgu32[((size_t)b * N_ + n) * 128 + cp];
        sx += lo16(u); sy += hi16(u);
    }
    if (ph == 1) { xp[2 * cp] = sx; xp[2 * cp + 1] = sy; }
    __syncthreads();
    if (ph == 0) {
        xp[2 * cp]     = (xp[2 * cp] + sx) * (1.0f / 64.0f);
        xp[2 * cp + 1] = (xp[2 * cp + 1] + sy) * (1.0f / 64.0f);
    }
    __syncthreads();

    float acc = xp[t];
    float mean = block_sum(acc, red) * (1.0f / C_);
    float dv = acc - mean;
    float var = block_sum(dv * dv, red) * (1.0f / C_);
    float xpv = dv * rsqrtf(var + 1e-5f) * ln_g[t] + ln_b[t];
    __syncthreads();
    xp[t] = xpv;
    __syncthreads();

    float ak = bkv[t];
    float av = bkv[C_ + t];
    for (int c = 0; c < C_; c++) {
        float xv = xp[c];
        ak += xv * Wkv[c * 2 * C_ + t];
        av += xv * Wkv[c * 2 * C_ + C_ + t];
    }
    float nk = fmaxf(sqrtf(half_reduce(ak * ak)), 1e-12f);
    kpn_u[(size_t)cell * C_ + t] = f2bf_u(ak / nk);
    vpT[((size_t)b * 256 + t) * 64 + p] = f2bf_u(av);
}

// ---------------- qkav: MFMA QK + fused tokc MFMA + softmax + MFMA PV ----------------
__global__ __launch_bounds__(256) void k_qkav(
    const ushort* __restrict__ qnu,   // [B*N][256] bf16
    const uint32_t* __restrict__ knu, // [B*N][128] bf16 pairs
    const ushort* __restrict__ kpnu,  // [B*P][256] bf16
    const ushort* __restrict__ TD,    // [320][256] bf16 block-diag tok matrix
    const float* __restrict__ biasT,  // [320] f32
    const ushort* __restrict__ vT,    // [B*256][60][64] bf16, zero-padded image
    const ushort* __restrict__ vpT,   // [B*256][64] bf16, keys padded to 64
    ushort* __restrict__ preu)        // [B*N][256] bf16 out
{
    const int tile = blockIdx.x;          // 0..195
    const int b  = blockIdx.y >> 1;
    const int hs = blockIdx.y & 1;        // heads hs*4 .. hs*4+3
    const int ty = tile / 14, tx = tile % 14;
    const int t = threadIdx.x;

    // ks (64*KS2=8704 us) aliased by coefW [4][16][CPAD] + coefP [4][16][CPAD] (10240 us)
    __shared__ __align__(16) ushort shmem[2 * 4 * 16 * CPAD];
    __shared__ ushort tokcS[16 * 136];
    ushort* ks = shmem;
    ushort* coefW = shmem;
    ushort* coefP = shmem + 4 * 16 * CPAD;

    uint32_t* ks32 = (uint32_t*)ks;
    for (int idx = t; idx < 64 * 32; idx += 256) {
        int r = idx >> 5, u2 = idx & 31;
        int gy = ty * 4 + (r >> 3) - 2, gx = tx * 4 + (r & 7) - 2;
        uint2 kv = make_uint2(0u, 0u);
        if (gy >= 0 && gy < H_ && gx >= 0 && gx < W_)
            kv = *reinterpret_cast<const uint2*>(
                knu + ((size_t)b * N_ + gy * W_ + gx) * 128 + hs * 64 + 2 * u2);
        ks32[r * (KS2 / 2) + 2 * u2]     = kv.x;
        ks32[r * (KS2 / 2) + 2 * u2 + 1] = kv.y;
    }
    __syncthreads();

    const int w = t >> 6, lane = t & 63;
    const int h = hs * 4 + w;
    const int col = lane & 15, kslc = lane >> 4;

    int r8[4], c8[4]; bool inb[4]; int pcl[4]; bool pval[4];
#pragma unroll
    for (int ct = 0; ct < 4; ct++) {
        int key = ct * 16 + col;
        r8[ct] = key >> 3; c8[ct] = key & 7;
        int gy = ty * 4 + r8[ct] - 2, gx = tx * 4 + c8[ct] - 2;
        inb[ct] = (gy >= 0) && (gy < H_) && (gx >= 0) && (gx < W_);
        pval[ct] = key < P_;
        pcl[ct] = pval[ct] ? key : (P_ - 1);
    }

    // QK phase (A: token=col, k-band = head h)
    size_t aflat = (size_t)b * N_ + (ty * 4 + (col >> 2)) * W_ + tx * 4 + (col & 3);
    short8 a = *(const short8*)(qnu + aflat * 256 + h * 32 + kslc * 8);

    f32x4 aw[4], ap[4];
#pragma unroll
    for (int ct = 0; ct < 4; ct++) {
        short8 bw = *(const short8*)(ks + (ct * 16 + col) * KS2 + w * 32 + kslc * 8);
        aw[ct] = __builtin_amdgcn_mfma_f32_16x16x32_bf16(a, bw, (f32x4){0.f,0.f,0.f,0.f}, 0, 0, 0);
        short8 bp = *(const short8*)(kpnu + ((size_t)b * P_ + pcl[ct]) * 256 + h * 32 + kslc * 8);
        ap[ct] = __builtin_amdgcn_mfma_f32_16x16x32_bf16(a, bp, (f32x4){0.f,0.f,0.f,0.f}, 0, 0, 0);
    }

    // fused tokc: same A fragment x TD block-diag (3 ctiles cover 34 cols)
    f32x4 at[3];
#pragma unroll
    for (int ct = 0; ct < 3; ct++) {
        short8 bt = *(const short8*)(TD + (size_t)(h * 34 + ct * 16 + col) * 256 + h * 32 + kslc * 8);
        at[ct] = __builtin_amdgcn_mfma_f32_16x16x32_bf16(a, bt, (f32x4){0.f,0.f,0.f,0.f}, 0, 0, 0);
    }
#pragma unroll
    for (int ct = 0; ct < 3; ct++) {
        int l = ct * 16 + col;
        if (l < 34) {
            float bT = biasT[h * 34 + l];
#pragma unroll
            for (int j = 0; j < 4; j++)
                tokcS[(kslc * 4 + j) * 136 + w * 34 + l] = f2bf_u(at[ct][j] + bT);
        }
    }

    __syncthreads();   // ks reads + tokcS writes done before coef (aliased) writes / tokc reads

    // softmax per token row j (token = (kslc, j)); write coef into A-frag LDS layout
#pragma unroll
    for (int j = 0; j < 4; j++) {
        float mj = -INFINITY;
#pragma unroll
        for (int ct = 0; ct < 4; ct++) {
            int dy = r8[ct] - kslc - 2, dx = c8[ct] - j - 2;
            bool win = inb[ct] && dy >= -2 && dy <= 2 && dx >= -2 && dx <= 2;
            if (win) mj = fmaxf(mj, aw[ct][j]);
            if (pval[ct]) mj = fmaxf(mj, ap[ct][j]);
        }
        mj = fmaxf(mj, __shfl_xor(mj, 1)); mj = fmaxf(mj, __shfl_xor(mj, 2));
        mj = fmaxf(mj, __shfl_xor(mj, 4)); mj = fmaxf(mj, __shfl_xor(mj, 8));
        float ej = 0.f;
        float ew[4], ep[4];
#pragma unroll
        for (int ct = 0; ct < 4; ct++) {
            int dy = r8[ct] - kslc - 2, dx = c8[ct] - j - 2;
            bool win = inb[ct] && dy >= -2 && dy <= 2 && dx >= -2 && dx <= 2;
            bool inner = dy >= -1 && dy <= 1 && dx >= -1 && dx <= 1;
            ew[ct] = win ? (inner ? 2.0f : 1.0f) * __expf(aw[ct][j] - mj) : 0.f;
            ep[ct] = pval[ct] ? __expf(ap[ct][j] - mj) : 0.f;
            ej += ew[ct] + ep[ct];
        }
        ej += __shfl_xor(ej, 1); ej += __shfl_xor(ej, 2);
        ej += __shfl_xor(ej, 4); ej += __shfl_xor(ej, 8);
        float sc = 1.0f / ej;
        const ushort* tokc_j = tokcS + (kslc * 4 + j) * 136 + w * 34;
        const int trow = (w * 16 + kslc * 4 + j) * CPAD;
#pragma unroll
        for (int ct = 0; ct < 4; ct++) {
            int dy = r8[ct] - kslc - 2, dx = c8[ct] - j - 2;
            float cw = 0.f;
            if (dy >= -2 && dy <= 2 && dx >= -2 && dx <= 2) {
                bool inner = dy >= -1 && dy <= 1 && dx >= -1 && dx <= 1;
                int l25 = (dy + 2) * 5 + (dx + 2);
                float tm = bfu2f(tokc_j[9 + l25]);
                if (inner) tm += bfu2f(tokc_j[(dy + 1) * 3 + (dx + 1)]);
                cw = ew[ct] * sc + tm;       // image-OOB: ew=0 -> tm; vT=0 kills it
            }
            coefW[trow + ct * 16 + col] = f2bf_u(cw);
            coefP[trow + ct * 16 + col] = f2bf_u(pval[ct] ? ep[ct] * sc : 0.f);
        }
    }
    __syncthreads();

    // PV phase: per wave = head w; D[tok16][ch32] = coefW·vT + coefP·vpT
    f32x4 accO[2];
    accO[0] = (f32x4){0.f,0.f,0.f,0.f};
    accO[1] = (f32x4){0.f,0.f,0.f,0.f};
    __builtin_amdgcn_s_setprio(1);
#pragma unroll
    for (int kc = 0; kc < 2; kc++) {
        short8 aWf = *(const short8*)(coefW + (w * 16 + col) * CPAD + kc * 32 + kslc * 8);
        short8 aPf = *(const short8*)(coefP + (w * 16 + col) * CPAD + kc * 32 + kslc * 8);
#pragma unroll
        for (int ct = 0; ct < 2; ct++) {
            int chg = hs * 128 + w * 32 + ct * 16 + col;
            size_t vbase = (((size_t)(b * 256 + chg)) * VTH + ty * 4 + kc * 4 + kslc) * VTW + tx * 4;
            uint2 l0 = *(const uint2*)(vT + vbase);
            uint2 l1 = *(const uint2*)(vT + vbase + 4);
            U8 ub; ub.u = make_uint4(l0.x, l0.y, l1.x, l1.y);
            accO[ct] = __builtin_amdgcn_mfma_f32_16x16x32_bf16(aWf, ub.s, accO[ct], 0, 0, 0);
            short8 bPf = *(const short8*)(vpT + ((size_t)b * 256 + chg) * 64 + kc * 32 + kslc * 8);
            accO[ct] = __builtin_amdgcn_mfma_f32_16x16x32_bf16(aPf, bPf, accO[ct], 0, 0, 0);
        }
    }
    __builtin_amdgcn_s_setprio(0);
    // store: C row = kslc*4+j -> token (iy=kslc, ix=j); col -> ch
#pragma unroll
    for (int ct = 0; ct < 2; ct++) {
        int chg = hs * 128 + w * 32 + ct * 16 + col;
#pragma unroll
        for (int j = 0; j < 4; j++) {
            size_t pflat = (size_t)b * N_ + (ty * 4 + kslc) * W_ + tx * 4 + j;
            preu[pflat * 256 + chg] = f2bf_u(accO[ct][j]);
        }
    }
}

extern "C" void kernel_launch(void* const* d_in, const int* in_sizes, int n_in,
                              void* d_out, int out_size, void* d_ws, size_t ws_size,
                              hipStream_t stream)
{
    (void)in_sizes; (void)n_in; (void)out_size; (void)ws_size;
    const float* x     = (const float*)d_in[0];
    const float* Wq    = (const float*)d_in[1];
    const float* bq    = (const float*)d_in[2];
    const float* Wkv   = (const float*)d_in[3];
    const float* bkv   = (const float*)d_in[4];
    const float* Wsr   = (const float*)d_in[5];
    const float* bsr   = (const float*)d_in[6];
    const float* ln_g  = (const float*)d_in[7];
    const float* ln_b  = (const float*)d_in[8];
    const float* tok1  = (const float*)d_in[9];
    const float* bias1 = (const float*)d_in[10];
    const float* tok2  = (const float*)d_in[11];
    const float* bias2 = (const float*)d_in[12];
    const float* Wproj = (const float*)d_in[13];
    const float* bproj = (const float*)d_in[14];
    float* out = (float*)d_out;

    const size_t nhalf = (size_t)B_ * N_ * 128;        // dwords per bf16 plane
    const size_t nvt   = (size_t)B_ * 256 * VTH * VTW; // ushorts

    uint32_t* knu    = (uint32_t*)d_ws;
    uint32_t* srgu   = knu + nhalf;                // sr-gelu plane, reused as pre
    uint32_t* qnu32  = srgu + nhalf;
    ushort*   vTus   = (ushort*)(qnu32 + nhalf);   // zero-padded transposed v image
    ushort*   WTus   = vTus + nvt;                 // 1024*256 bf16
    ushort*   WTpus  = WTus + 1024 * 256;          // 256*256 bf16
    ushort*   TDus   = WTpus + 256 * 256;          // 320*256 bf16
    float*    biasT  = (float*)(TDus + 320 * 256); // 320 f32
    ushort*   vpTus  = (ushort*)(biasT + 320);     // B*256*64 bf16 (transposed vp)
    ushort*   kpnuS  = vpTus + (size_t)B_ * 256 * 64;  // B*P*256 bf16

    ushort* qnu = (ushort*)qnu32;

    k_prep<<<512, 256, 0, stream>>>(Wq, Wkv, Wsr, Wproj, tok1, bias1, tok2, bias2,
                                    WTus, WTpus, TDus, biasT,
                                    vTus, (uint32_t*)vpTus);
    k_gemm_in<<<dim3(196, 2), 256, 0, stream>>>(x, WTus, bq, bkv, bsr,
                                                qnu, (ushort*)knu, vTus, (ushort*)srgu);
    k_srt<<<B_ * P_, 256, 0, stream>>>(srgu, Wkv, bkv, ln_g, ln_b, kpnuS, vpTus);
    k_qkav<<<dim3(196, B_ * 2), 256, 0, stream>>>(qnu, knu, kpnuS, TDus, biasT,
                                                  vTus, vpTus, (ushort*)srgu);
    k_gemm_proj<<<dim3(196, 4), 256, 0, stream>>>((ushort*)srgu, WTpus, bproj, out);
}

// Round 20
// 106.340 us; speedup vs baseline: 1.5468x; 1.0313x over previous
//
#include <hip/hip_runtime.h>
#include <hip/hip_bf16.h>

using bf16 = __hip_bfloat16;

#define B_  4
#define H_  56
#define W_  56
#define N_  3136
#define C_  256
#define NH  8
#define HD  32
#define P_  49
#define PH  7
#define TOKC 272         // 8 heads * 34 token coefficients
#define KS2  136         // k-window LDS row stride in ushorts (128-ch slice + 8 pad)
#define CPAD 80          // coef LDS row stride (ushorts): 160B, 16B-aligned fragments
#define VTH  60          // vT padded height (y+2 in [0,60))
#define VTW  64          // vT padded width  (x+2 in [0,64))

typedef __attribute__((ext_vector_type(8))) short short8;
typedef __attribute__((ext_vector_type(4))) float f32x4;

union U8 { uint4 u; short8 s; };

__device__ __forceinline__ float bfu2f(ushort u) { return __uint_as_float((uint32_t)u << 16); }
__device__ __forceinline__ ushort f2bf_u(float f) {
    uint32_t u = __float_as_uint(f);
    uint32_t r = (u + 0x7FFFu + ((u >> 16) & 1u)) >> 16;
    return (ushort)r;
}
__device__ __forceinline__ uint32_t pk2(float a, float b) {
    return (uint32_t)f2bf_u(a) | ((uint32_t)f2bf_u(b) << 16);
}
__device__ __forceinline__ float lo16(uint32_t u) { return __uint_as_float(u << 16); }
__device__ __forceinline__ float hi16(uint32_t u) { return __uint_as_float(u & 0xffff0000u); }

__device__ __forceinline__ float half_reduce(float v) {
#pragma unroll
    for (int m = 16; m >= 1; m >>= 1) v += __shfl_xor(v, m);
    return v;
}

__device__ __forceinline__ float block_sum(float val, float* red) {
#pragma unroll
    for (int m = 32; m >= 1; m >>= 1) val += __shfl_xor(val, m);
    __syncthreads();
    if ((threadIdx.x & 63) == 0) red[threadIdx.x >> 6] = val;
    __syncthreads();
    return red[0] + red[1] + red[2] + red[3];
}

// ---------------- prep: weight transposes + tok block-diag + border-zero vT/vpT ----------------
__global__ __launch_bounds__(256) void k_prep(
    const float* __restrict__ Wq, const float* __restrict__ Wkv,
    const float* __restrict__ Wsr, const float* __restrict__ Wproj,
    const float* __restrict__ tok1, const float* __restrict__ bias1,
    const float* __restrict__ tok2, const float* __restrict__ bias2,
    ushort* __restrict__ WT, ushort* __restrict__ WTp,
    ushort* __restrict__ TD, float* __restrict__ biasT,
    ushort* __restrict__ vT, uint32_t* __restrict__ vpT32)
{
    const int gid = blockIdx.x * 256 + threadIdx.x;
    const int gs = gridDim.x * 256;
    for (int i = gid; i < 1024 * 256; i += gs) {
        int o = i >> 8, c = i & 255;
        float w = (o < 256) ? Wq[c * 256 + o]
                : (o < 768) ? Wkv[c * 512 + (o - 256)]
                            : Wsr[c * 256 + (o - 768)];
        WT[i] = f2bf_u(w);
    }
    for (int i = gid; i < 256 * 256; i += gs) {
        int o = i >> 8, c = i & 255;
        WTp[i] = f2bf_u(Wproj[c * 256 + o]);
    }
    for (int i = gid; i < 320 * 256; i += gs) {
        int j = i >> 8, k = i & 255;
        float val = 0.f;
        if (j < TOKC) {
            int h = j / 34, l = j % 34;
            if ((k >> 5) == h) {
                int d = k & 31;
                val = (l < 9) ? tok1[(h * HD + d) * 9 + l]
                              : tok2[(h * HD + d) * 25 + (l - 9)];
            }
        }
        TD[i] = f2bf_u(val);
    }
    for (int i = gid; i < 320; i += gs) {
        float bv = 0.f;
        if (i < TOKC) {
            int h = i / 34, l = i % 34;
            bv = (l < 9) ? bias1[h * 9 + l] : bias2[h * 25 + (l - 9)];
        }
        biasT[i] = bv;
    }
    // zero only the padding border of vT (interior fully overwritten by gemm_in)
    const int nimg = B_ * 256;
    for (int i = gid; i < nimg * 704; i += gs) {
        int img = i / 704, c = i % 704;
        int y, x;
        if (c < 256) { int yi = c >> 6; y = (yi < 2) ? yi : yi + 56; x = c & 63; }
        else { int cc = c - 256; y = 2 + cc / 8; int xx = cc % 8; x = (xx < 2) ? xx : xx + 56; }
        vT[(size_t)img * VTH * VTW + y * VTW + x] = 0;
    }
    for (int i = gid; i < B_ * 256 * 32; i += gs) vpT32[i] = 0u;
}

// ---------------- merged input GEMM: 64 rows x 512 cols (8 chunks), K=256 ----------------
__global__ __launch_bounds__(256) void k_gemm_in(
    const float* __restrict__ xf,     // [12544][256] f32
    const ushort* __restrict__ WT,    // [1024][256] bf16
    const float* __restrict__ bq, const float* __restrict__ bkv,
    const float* __restrict__ bsr,
    ushort* __restrict__ qnu,
    ushort* __restrict__ knu, ushort* __restrict__ vT, ushort* __restrict__ srgu)
{
    const int r0 = blockIdx.x * 64;
    const int halfy = blockIdx.y;
    const int t = threadIdx.x;
    __shared__ __align__(16) ushort As[64 * 264];
    __shared__ __align__(16) ushort Bs[64 * 264];

#pragma unroll
    for (int i = 0; i < 8; i++) {
        int chunk = t + i * 256;
        int row = chunk >> 5, ks8 = (chunk & 31) * 8;
        const float* src = xf + (size_t)(r0 + row) * 256 + ks8;
        float4 f0 = *(const float4*)(src);
        float4 f1 = *(const float4*)(src + 4);
        uint4 o;
        o.x = pk2(f0.x, f0.y); o.y = pk2(f0.z, f0.w);
        o.z = pk2(f1.x, f1.y); o.w = pk2(f1.z, f1.w);
        *(uint4*)(As + row * 264 + ks8) = o;
    }
    __syncthreads();

    const int w = t >> 6, lane = t & 63;
    const int arow = w * 16 + (lane & 15);
    const int k0 = (lane >> 4) * 8;
    const int colq = lane & 15;
    const int rb = r0 + w * 16 + (lane >> 4) * 4;

    short8 areg[8];
#pragma unroll
    for (int kk = 0; kk < 8; kk++)
        areg[kk] = *(const short8*)(As + arow * 264 + kk * 32 + k0);

    for (int cc = 0; cc < 8; cc++) {
        const int cb = halfy * 512 + cc * 64;
        const int mode = cb >> 8;
        const int cm = cb & 255;

        __syncthreads();   // previous chunk's Bs reads done
#pragma unroll
        for (int i = 0; i < 8; i++) {
            int chunk = t + i * 256;
            int row = chunk >> 5, ks8 = (chunk & 31) * 8;
            *(uint4*)(Bs + row * 264 + ks8) =
                *(const uint4*)(WT + (size_t)(cb + row) * 256 + ks8);
        }
        __syncthreads();

        f32x4 acc[4];
#pragma unroll
        for (int ct = 0; ct < 4; ct++) acc[ct] = (f32x4){0.f, 0.f, 0.f, 0.f};
#pragma unroll
        for (int kk = 0; kk < 8; kk++) {
#pragma unroll
            for (int ct = 0; ct < 4; ct++) {
                short8 b = *(const short8*)(Bs + (ct * 16 + colq) * 264 + kk * 32 + k0);
                acc[ct] = __builtin_amdgcn_mfma_f32_16x16x32_bf16(areg[kk], b, acc[ct], 0, 0, 0);
            }
        }

        const float* bp = (mode == 0) ? bq : (mode == 1) ? bkv : (mode == 2) ? (bkv + 256) : bsr;
#pragma unroll
        for (int ct = 0; ct < 4; ct++) {
            float bv = bp[cm + ct * 16 + colq];
#pragma unroll
            for (int j = 0; j < 4; j++) acc[ct][j] += bv;
        }

        if (mode <= 1) {
#pragma unroll
            for (int hp = 0; hp < 2; hp++) {
#pragma unroll
                for (int j = 0; j < 4; j++) {
                    float ss = acc[2 * hp][j] * acc[2 * hp][j] + acc[2 * hp + 1][j] * acc[2 * hp + 1][j];
                    ss += __shfl_xor(ss, 1); ss += __shfl_xor(ss, 2);
                    ss += __shfl_xor(ss, 4); ss += __shfl_xor(ss, 8);
                    float inv = 1.0f / fmaxf(sqrtf(ss), 1e-12f);
                    acc[2 * hp][j] *= inv; acc[2 * hp + 1][j] *= inv;
                }
            }
        } else if (mode == 3) {
#pragma unroll
            for (int ct = 0; ct < 4; ct++)
#pragma unroll
                for (int j = 0; j < 4; j++) {
                    float s = acc[ct][j];
                    acc[ct][j] = 0.5f * s * (1.0f + erff(s * 0.70710678118654752f));
                }
        }

#pragma unroll
        for (int ct = 0; ct < 4; ct++) {
            int gcol = cm + ct * 16 + colq;
#pragma unroll
            for (int j = 0; j < 4; j++) {
                float vvv = acc[ct][j];
                size_t ro = (size_t)(rb + j);
                if (mode == 0)      qnu[ro * 256 + gcol] = f2bf_u(vvv);
                else if (mode == 1) knu[ro * 256 + gcol] = f2bf_u(vvv);
                else if (mode == 2) {
                    int bb = (int)(ro / N_), n = (int)(ro % N_);
                    int yy = n / W_, xx = n % W_;
                    vT[((size_t)(bb * 256 + gcol) * VTH + yy + 2) * VTW + xx + 2] = f2bf_u(vvv);
                } else {
                    srgu[ro * 256 + gcol] = f2bf_u(vvv);
                }
            }
        }
    }
}

// ---------------- bf16-A GEMM 64x64 tile, K=256 (proj, f32 -> out) ----------------
__global__ __launch_bounds__(256) void k_gemm_proj(
    const ushort* __restrict__ Abf,
    const ushort* __restrict__ WT,
    const float*  __restrict__ bias,
    float* __restrict__ dstF)
{
    const int r0 = blockIdx.x * 64;
    const int cb = blockIdx.y * 64;
    const int t = threadIdx.x;
    __shared__ __align__(16) ushort As[64 * 264];
    __shared__ __align__(16) ushort Bs[64 * 264];

#pragma unroll
    for (int i = 0; i < 8; i++) {
        int chunk = t + i * 256;
        int row = chunk >> 5, ks = (chunk & 31) * 8;
        *(uint4*)(As + row * 264 + ks) = *(const uint4*)(Abf + (size_t)(r0 + row) * 256 + ks);
        *(uint4*)(Bs + row * 264 + ks) = *(const uint4*)(WT + (size_t)(cb + row) * 256 + ks);
    }
    __syncthreads();

    const int w = t >> 6, lane = t & 63;
    const int arow = w * 16 + (lane & 15);
    const int k0 = (lane >> 4) * 8;
    f32x4 acc[4];
#pragma unroll
    for (int ct = 0; ct < 4; ct++) acc[ct] = (f32x4){0.f, 0.f, 0.f, 0.f};

#pragma unroll
    for (int kk = 0; kk < 8; kk++) {
        short8 a = *(const short8*)(As + arow * 264 + kk * 32 + k0);
#pragma unroll
        for (int ct = 0; ct < 4; ct++) {
            short8 b = *(const short8*)(Bs + (ct * 16 + (lane & 15)) * 264 + kk * 32 + k0);
            acc[ct] = __builtin_amdgcn_mfma_f32_16x16x32_bf16(a, b, acc[ct], 0, 0, 0);
        }
    }

    const int colq = lane & 15;
    const int rb = r0 + w * 16 + (lane >> 4) * 4;
#pragma unroll
    for (int ct = 0; ct < 4; ct++) {
        float bv = bias[cb + ct * 16 + colq];
#pragma unroll
        for (int j = 0; j < 4; j++) acc[ct][j] += bv;
    }

#pragma unroll
    for (int ct = 0; ct < 4; ct++) {
        int gcol = cb + ct * 16 + colq;
#pragma unroll
        for (int j = 0; j < 4; j++)
            dstF[(size_t)(rb + j) * 256 + gcol] = acc[ct][j];
    }
}

// ---------------- srt: pool + LN + kv proj + normalize; vp stored transposed ----------------
__global__ __launch_bounds__(256) void k_srt(
    const uint32_t* __restrict__ srgu32,
    const float* __restrict__ Wkv, const float* __restrict__ bkv,
    const float* __restrict__ ln_g, const float* __restrict__ ln_b,
    ushort* __restrict__ kpn_u, ushort* __restrict__ vpT)
{
    const int cell = blockIdx.x;   // b*P + p
    const int b = cell / P_, p = cell % P_;
    const int py = p / PH, px = p % PH;
    const int t = threadIdx.x;
    const int ph = t >> 7, cp = t & 127;
    __shared__ float xp[C_];
    __shared__ float red[4];

    float sx = 0.f, sy = 0.f;
    for (int k = 0; k < 32; k++) {
        int pi = ph * 32 + k;
        int n = (py * 8 + (pi >> 3)) * W_ + px * 8 + (pi & 7);
        uint32_t u = srgu32[((size_t)b * N_ + n) * 128 + cp];
        sx += lo16(u); sy += hi16(u);
    }
    if (ph == 1) { xp[2 * cp] = sx; xp[2 * cp + 1] = sy; }
    __syncthreads();
    if (ph == 0) {
        xp[2 * cp]     = (xp[2 * cp] + sx) * (1.0f / 64.0f);
        xp[2 * cp + 1] = (xp[2 * cp + 1] + sy) * (1.0f / 64.0f);
    }
    __syncthreads();

    float acc = xp[t];
    float mean = block_sum(acc, red) * (1.0f / C_);
    float dv = acc - mean;
    float var = block_sum(dv * dv, red) * (1.0f / C_);
    float xpv = dv * rsqrtf(var + 1e-5f) * ln_g[t] + ln_b[t];
    __syncthreads();
    xp[t] = xpv;
    __syncthreads();

    float ak = bkv[t];
    float av = bkv[C_ + t];
    for (int c = 0; c < C_; c++) {
        float xv = xp[c];
        ak += xv * Wkv[c * 2 * C_ + t];
        av += xv * Wkv[c * 2 * C_ + C_ + t];
    }
    float nk = fmaxf(sqrtf(half_reduce(ak * ak)), 1e-12f);
    kpn_u[(size_t)cell * C_ + t] = f2bf_u(ak / nk);
    vpT[((size_t)b * 256 + t) * 64 + p] = f2bf_u(av);
}

// ---------------- qkav: MFMA QK + fused tokc MFMA + softmax + MFMA PV ----------------
__global__ __launch_bounds__(256) void k_qkav(
    const ushort* __restrict__ qnu,   // [B*N][256] bf16
    const uint32_t* __restrict__ knu, // [B*N][128] bf16 pairs
    const ushort* __restrict__ kpnu,  // [B*P][256] bf16
    const ushort* __restrict__ TD,    // [320][256] bf16 block-diag tok matrix
    const float* __restrict__ biasT,  // [320] f32
    const ushort* __restrict__ vT,    // [B*256][60][64] bf16, zero-padded image
    const ushort* __restrict__ vpT,   // [B*256][64] bf16, keys padded to 64
    ushort* __restrict__ preu)        // [B*N][256] bf16 out
{
    const int tile = blockIdx.x;          // 0..195
    const int b  = blockIdx.y >> 1;
    const int hs = blockIdx.y & 1;        // heads hs*4 .. hs*4+3
    const int ty = tile / 14, tx = tile % 14;
    const int t = threadIdx.x;

    // ks (64*KS2=8704 us) aliased by coefW [4][16][CPAD] + coefP [4][16][CPAD] (10240 us)
    __shared__ __align__(16) ushort shmem[2 * 4 * 16 * CPAD];
    __shared__ ushort tokcS[16 * 136];
    ushort* ks = shmem;
    ushort* coefW = shmem;
    ushort* coefP = shmem + 4 * 16 * CPAD;

    uint32_t* ks32 = (uint32_t*)ks;
    for (int idx = t; idx < 64 * 32; idx += 256) {
        int r = idx >> 5, u2 = idx & 31;
        int gy = ty * 4 + (r >> 3) - 2, gx = tx * 4 + (r & 7) - 2;
        uint2 kv = make_uint2(0u, 0u);
        if (gy >= 0 && gy < H_ && gx >= 0 && gx < W_)
            kv = *reinterpret_cast<const uint2*>(
                knu + ((size_t)b * N_ + gy * W_ + gx) * 128 + hs * 64 + 2 * u2);
        ks32[r * (KS2 / 2) + 2 * u2]     = kv.x;
        ks32[r * (KS2 / 2) + 2 * u2 + 1] = kv.y;
    }
    __syncthreads();

    const int w = t >> 6, lane = t & 63;
    const int h = hs * 4 + w;
    const int col = lane & 15, kslc = lane >> 4;

    int r8[4], c8[4]; bool inb[4]; int pcl[4]; bool pval[4];
#pragma unroll
    for (int ct = 0; ct < 4; ct++) {
        int key = ct * 16 + col;
        r8[ct] = key >> 3; c8[ct] = key & 7;
        int gy = ty * 4 + r8[ct] - 2, gx = tx * 4 + c8[ct] - 2;
        inb[ct] = (gy >= 0) && (gy < H_) && (gx >= 0) && (gx < W_);
        pval[ct] = key < P_;
        pcl[ct] = pval[ct] ? key : (P_ - 1);
    }

    // QK phase (A: token=col, k-band = head h)
    size_t aflat = (size_t)b * N_ + (ty * 4 + (col >> 2)) * W_ + tx * 4 + (col & 3);
    short8 a = *(const short8*)(qnu + aflat * 256 + h * 32 + kslc * 8);

    f32x4 aw[4], ap[4];
#pragma unroll
    for (int ct = 0; ct < 4; ct++) {
        short8 bw = *(const short8*)(ks + (ct * 16 + col) * KS2 + w * 32 + kslc * 8);
        aw[ct] = __builtin_amdgcn_mfma_f32_16x16x32_bf16(a, bw, (f32x4){0.f,0.f,0.f,0.f}, 0, 0, 0);
        short8 bp = *(const short8*)(kpnu + ((size_t)b * P_ + pcl[ct]) * 256 + h * 32 + kslc * 8);
        ap[ct] = __builtin_amdgcn_mfma_f32_16x16x32_bf16(a, bp, (f32x4){0.f,0.f,0.f,0.f}, 0, 0, 0);
    }

    // fused tokc: same A fragment x TD block-diag (3 ctiles cover 34 cols)
    f32x4 at[3];
#pragma unroll
    for (int ct = 0; ct < 3; ct++) {
        short8 bt = *(const short8*)(TD + (size_t)(h * 34 + ct * 16 + col) * 256 + h * 32 + kslc * 8);
        at[ct] = __builtin_amdgcn_mfma_f32_16x16x32_bf16(a, bt, (f32x4){0.f,0.f,0.f,0.f}, 0, 0, 0);
    }
#pragma unroll
    for (int ct = 0; ct < 3; ct++) {
        int l = ct * 16 + col;
        if (l < 34) {
            float bT = biasT[h * 34 + l];
#pragma unroll
            for (int j = 0; j < 4; j++)
                tokcS[(kslc * 4 + j) * 136 + w * 34 + l] = f2bf_u(at[ct][j] + bT);
        }
    }

    __syncthreads();   // ks reads + tokcS writes done before coef (aliased) writes / tokc reads

    // softmax per token row j (token = (kslc, j)); write coef into A-frag LDS layout
#pragma unroll
    for (int j = 0; j < 4; j++) {
        float mj = -INFINITY;
#pragma unroll
        for (int ct = 0; ct < 4; ct++) {
            int dy = r8[ct] - kslc - 2, dx = c8[ct] - j - 2;
            bool win = inb[ct] && dy >= -2 && dy <= 2 && dx >= -2 && dx <= 2;
            if (win) mj = fmaxf(mj, aw[ct][j]);
            if (pval[ct]) mj = fmaxf(mj, ap[ct][j]);
        }
        mj = fmaxf(mj, __shfl_xor(mj, 1)); mj = fmaxf(mj, __shfl_xor(mj, 2));
        mj = fmaxf(mj, __shfl_xor(mj, 4)); mj = fmaxf(mj, __shfl_xor(mj, 8));
        float ej = 0.f;
        float ew[4], ep[4];
#pragma unroll
        for (int ct = 0; ct < 4; ct++) {
            int dy = r8[ct] - kslc - 2, dx = c8[ct] - j - 2;
            bool win = inb[ct] && dy >= -2 && dy <= 2 && dx >= -2 && dx <= 2;
            bool inner = dy >= -1 && dy <= 1 && dx >= -1 && dx <= 1;
            ew[ct] = win ? (inner ? 2.0f : 1.0f) * __expf(aw[ct][j] - mj) : 0.f;
            ep[ct] = pval[ct] ? __expf(ap[ct][j] - mj) : 0.f;
            ej += ew[ct] + ep[ct];
        }
        ej += __shfl_xor(ej, 1); ej += __shfl_xor(ej, 2);
        ej += __shfl_xor(ej, 4); ej += __shfl_xor(ej, 8);
        float sc = 1.0f / ej;
        const ushort* tokc_j = tokcS + (kslc * 4 + j) * 136 + w * 34;
        const int trow = (w * 16 + kslc * 4 + j) * CPAD;
#pragma unroll
        for (int ct = 0; ct < 4; ct++) {
            int dy = r8[ct] - kslc - 2, dx = c8[ct] - j - 2;
            float cw = 0.f;
            if (dy >= -2 && dy <= 2 && dx >= -2 && dx <= 2) {
                bool inner = dy >= -1 && dy <= 1 && dx >= -1 && dx <= 1;
                int l25 = (dy + 2) * 5 + (dx + 2);
                float tm = bfu2f(tokc_j[9 + l25]);
                if (inner) tm += bfu2f(tokc_j[(dy + 1) * 3 + (dx + 1)]);
                cw = ew[ct] * sc + tm;       // image-OOB: ew=0 -> tm; vT=0 kills it
            }
            coefW[trow + ct * 16 + col] = f2bf_u(cw);
            coefP[trow + ct * 16 + col] = f2bf_u(pval[ct] ? ep[ct] * sc : 0.f);
        }
    }
    __syncthreads();

    // PV phase: per wave = head w; D[tok16][ch32] = coefW·vT + coefP·vpT
    f32x4 accO[2];
    accO[0] = (f32x4){0.f,0.f,0.f,0.f};
    accO[1] = (f32x4){0.f,0.f,0.f,0.f};
#pragma unroll
    for (int kc = 0; kc < 2; kc++) {
        short8 aWf = *(const short8*)(coefW + (w * 16 + col) * CPAD + kc * 32 + kslc * 8);
        short8 aPf = *(const short8*)(coefP + (w * 16 + col) * CPAD + kc * 32 + kslc * 8);
#pragma unroll
        for (int ct = 0; ct < 2; ct++) {
            int chg = hs * 128 + w * 32 + ct * 16 + col;
            size_t vbase = (((size_t)(b * 256 + chg)) * VTH + ty * 4 + kc * 4 + kslc) * VTW + tx * 4;
            uint2 l0 = *(const uint2*)(vT + vbase);
            uint2 l1 = *(const uint2*)(vT + vbase + 4);
            U8 ub; ub.u = make_uint4(l0.x, l0.y, l1.x, l1.y);
            accO[ct] = __builtin_amdgcn_mfma_f32_16x16x32_bf16(aWf, ub.s, accO[ct], 0, 0, 0);
            short8 bPf = *(const short8*)(vpT + ((size_t)b * 256 + chg) * 64 + kc * 32 + kslc * 8);
            accO[ct] = __builtin_amdgcn_mfma_f32_16x16x32_bf16(aPf, bPf, accO[ct], 0, 0, 0);
        }
    }
    // store: C row = kslc*4+j -> token (iy=kslc, ix=j); col -> ch
#pragma unroll
    for (int ct = 0; ct < 2; ct++) {
        int chg = hs * 128 + w * 32 + ct * 16 + col;
#pragma unroll
        for (int j = 0; j < 4; j++) {
            size_t pflat = (size_t)b * N_ + (ty * 4 + kslc) * W_ + tx * 4 + j;
            preu[pflat * 256 + chg] = f2bf_u(accO[ct][j]);
        }
    }
}

extern "C" void kernel_launch(void* const* d_in, const int* in_sizes, int n_in,
                              void* d_out, int out_size, void* d_ws, size_t ws_size,
                              hipStream_t stream)
{
    (void)in_sizes; (void)n_in; (void)out_size; (void)ws_size;
    const float* x     = (const float*)d_in[0];
    const float* Wq    = (const float*)d_in[1];
    const float* bq    = (const float*)d_in[2];
    const float* Wkv   = (const float*)d_in[3];
    const float* bkv   = (const float*)d_in[4];
    const float* Wsr   = (const float*)d_in[5];
    const float* bsr   = (const float*)d_in[6];
    const float* ln_g  = (const float*)d_in[7];
    const float* ln_b  = (const float*)d_in[8];
    const float* tok1  = (const float*)d_in[9];
    const float* bias1 = (const float*)d_in[10];
    const float* tok2  = (const float*)d_in[11];
    const float* bias2 = (const float*)d_in[12];
    const float* Wproj = (const float*)d_in[13];
    const float* bproj = (const float*)d_in[14];
    float* out = (float*)d_out;

    const size_t nhalf = (size_t)B_ * N_ * 128;        // dwords per bf16 plane
    const size_t nvt   = (size_t)B_ * 256 * VTH * VTW; // ushorts

    uint32_t* knu    = (uint32_t*)d_ws;
    uint32_t* srgu   = knu + nhalf;                // sr-gelu plane, reused as pre
    uint32_t* qnu32  = srgu + nhalf;
    ushort*   vTus   = (ushort*)(qnu32 + nhalf);   // zero-padded transposed v image
    ushort*   WTus   = vTus + nvt;                 // 1024*256 bf16
    ushort*   WTpus  = WTus + 1024 * 256;          // 256*256 bf16
    ushort*   TDus   = WTpus + 256 * 256;          // 320*256 bf16
    float*    biasT  = (float*)(TDus + 320 * 256); // 320 f32
    ushort*   vpTus  = (ushort*)(biasT + 320);     // B*256*64 bf16 (transposed vp)
    ushort*   kpnuS  = vpTus + (size_t)B_ * 256 * 64;  // B*P*256 bf16

    ushort* qnu = (ushort*)qnu32;

    k_prep<<<512, 256, 0, stream>>>(Wq, Wkv, Wsr, Wproj, tok1, bias1, tok2, bias2,
                                    WTus, WTpus, TDus, biasT,
                                    vTus, (uint32_t*)vpTus);
    k_gemm_in<<<dim3(196, 2), 256, 0, stream>>>(x, WTus, bq, bkv, bsr,
                                                qnu, (ushort*)knu, vTus, (ushort*)srgu);
    k_srt<<<B_ * P_, 256, 0, stream>>>(srgu, Wkv, bkv, ln_g, ln_b, kpnuS, vpTus);
    k_qkav<<<dim3(196, B_ * 2), 256, 0, stream>>>(qnu, knu, kpnuS, TDus, biasT,
                                                  vTus, vpTus, (ushort*)srgu);
    k_gemm_proj<<<dim3(196, 4), 256, 0, stream>>>((ushort*)srgu, WTpus, bproj, out);
}